// Round 1
// baseline (2951.774 us; speedup 1.0000x reference)
//
#include <hip/hip_runtime.h>
#include <math.h>

static constexpr int S = 2048;          // tokens (B=1)
static constexpr int D = 1024;          // model dim
static constexpr int H = 16;            // heads
static constexpr int HD = 64;           // head dim
static constexpr int E = 8;             // experts
static constexpr int F = 2048;          // ffn dim
static constexpr int NSLOTS = S * 2;    // 4096 (every token picks exactly 2 experts)

// ======================= LayerNorm =======================
__global__ __launch_bounds__(256) void ln_kernel(const float* __restrict__ x,
    const float* __restrict__ w, const float* __restrict__ b, float* __restrict__ y)
{
    int t = blockIdx.x, tid = threadIdx.x;
    __shared__ float redx[256];
    __shared__ float redy[256];
    const float* xr = x + (size_t)t * D;
    float4 xv = *(const float4*)(xr + tid * 4);
    redx[tid] = xv.x + xv.y + xv.z + xv.w;
    redy[tid] = xv.x * xv.x + xv.y * xv.y + xv.z * xv.z + xv.w * xv.w;
    __syncthreads();
    for (int st = 128; st > 0; st >>= 1) {
        if (tid < st) { redx[tid] += redx[tid + st]; redy[tid] += redy[tid + st]; }
        __syncthreads();
    }
    float mean = redx[0] * (1.0f / D);
    float var  = redy[0] * (1.0f / D) - mean * mean;
    float rstd = rsqrtf(var + 1e-5f);
    float4 wv = *(const float4*)(w + tid * 4);
    float4 bv = *(const float4*)(b + tid * 4);
    float4 o;
    o.x = (xv.x - mean) * rstd * wv.x + bv.x;
    o.y = (xv.y - mean) * rstd * wv.y + bv.y;
    o.z = (xv.z - mean) * rstd * wv.z + bv.z;
    o.w = (xv.w - mean) * rstd * wv.w + bv.w;
    *(float4*)(y + (size_t)t * D + tid * 4) = o;
}

// ======================= RoPE (in-place on q,k) =======================
__global__ __launch_bounds__(512) void rope_kernel(float* __restrict__ q, float* __restrict__ k)
{
    int t = blockIdx.x;
    int idx = threadIdx.x;            // 0..511 = h*32 + i
    int h = idx >> 5, i = idx & 31;
    float invf = powf(10000.0f, -(float)i / 32.0f);
    float ang = (float)t * invf;
    float c = cosf(ang), s = sinf(ang);
    size_t base = (size_t)t * D + h * HD + i;
    float q1 = q[base], q2 = q[base + 32];
    q[base]      = q1 * c - q2 * s;
    q[base + 32] = q2 * c + q1 * s;
    float k1 = k[base], k2 = k[base + 32];
    k[base]      = k1 * c - k2 * s;
    k[base + 32] = k2 * c + k1 * s;
}

// ======================= QKV GEMM (fp32 64x64 tiles, z selects q/k/v) =======================
__global__ __launch_bounds__(256) void gemm_qkv(const float* __restrict__ A,
    const float* __restrict__ wq, const float* __restrict__ wk, const float* __restrict__ wv,
    float* __restrict__ qo, float* __restrict__ ko, float* __restrict__ vo)
{
    const float* B = blockIdx.z == 0 ? wq : (blockIdx.z == 1 ? wk : wv);
    float* C = blockIdx.z == 0 ? qo : (blockIdx.z == 1 ? ko : vo);
    const int Kd = D, N = D;
    __shared__ alignas(16) float As[16][68];
    __shared__ alignas(16) float Bs[16][68];
    int tid = threadIdx.x;
    int tx = tid & 15, ty = tid >> 4;
    int m0 = blockIdx.y * 64, n0 = blockIdx.x * 64;
    int ar = tid >> 2, ak = (tid & 3) * 4;
    float acc[4][4] = {};
    for (int k0 = 0; k0 < Kd; k0 += 16) {
        float4 a4 = *(const float4*)(A + (size_t)(m0 + ar) * Kd + k0 + ak);
        float4 b4 = *(const float4*)(B + (size_t)(k0 + ty) * N + n0 + tx * 4);
        As[ak + 0][ar] = a4.x; As[ak + 1][ar] = a4.y; As[ak + 2][ar] = a4.z; As[ak + 3][ar] = a4.w;
        *(float4*)&Bs[ty][tx * 4] = b4;
        __syncthreads();
#pragma unroll
        for (int kk = 0; kk < 16; kk++) {
            float4 av = *(const float4*)&As[kk][ty * 4];
            float4 bv = *(const float4*)&Bs[kk][tx * 4];
            float a_[4] = {av.x, av.y, av.z, av.w};
            float b_[4] = {bv.x, bv.y, bv.z, bv.w};
#pragma unroll
            for (int i = 0; i < 4; i++)
#pragma unroll
                for (int j = 0; j < 4; j++) acc[i][j] = fmaf(a_[i], b_[j], acc[i][j]);
        }
        __syncthreads();
    }
#pragma unroll
    for (int i = 0; i < 4; i++) {
        float4 o = make_float4(acc[i][0], acc[i][1], acc[i][2], acc[i][3]);
        *(float4*)(C + (size_t)(m0 + ty * 4 + i) * N + n0 + tx * 4) = o;
    }
}

// ======================= O-proj GEMM + residual =======================
__global__ __launch_bounds__(256) void gemm_wo(const float* __restrict__ A,
    const float* __restrict__ B, const float* __restrict__ resid, float* __restrict__ C)
{
    const int Kd = D, N = D;
    __shared__ alignas(16) float As[16][68];
    __shared__ alignas(16) float Bs[16][68];
    int tid = threadIdx.x;
    int tx = tid & 15, ty = tid >> 4;
    int m0 = blockIdx.y * 64, n0 = blockIdx.x * 64;
    int ar = tid >> 2, ak = (tid & 3) * 4;
    float acc[4][4] = {};
    for (int k0 = 0; k0 < Kd; k0 += 16) {
        float4 a4 = *(const float4*)(A + (size_t)(m0 + ar) * Kd + k0 + ak);
        float4 b4 = *(const float4*)(B + (size_t)(k0 + ty) * N + n0 + tx * 4);
        As[ak + 0][ar] = a4.x; As[ak + 1][ar] = a4.y; As[ak + 2][ar] = a4.z; As[ak + 3][ar] = a4.w;
        *(float4*)&Bs[ty][tx * 4] = b4;
        __syncthreads();
#pragma unroll
        for (int kk = 0; kk < 16; kk++) {
            float4 av = *(const float4*)&As[kk][ty * 4];
            float4 bv = *(const float4*)&Bs[kk][tx * 4];
            float a_[4] = {av.x, av.y, av.z, av.w};
            float b_[4] = {bv.x, bv.y, bv.z, bv.w};
#pragma unroll
            for (int i = 0; i < 4; i++)
#pragma unroll
                for (int j = 0; j < 4; j++) acc[i][j] = fmaf(a_[i], b_[j], acc[i][j]);
        }
        __syncthreads();
    }
#pragma unroll
    for (int i = 0; i < 4; i++) {
        size_t row = (size_t)(m0 + ty * 4 + i);
        float4 r4 = *(const float4*)(resid + row * N + n0 + tx * 4);
        float4 o = make_float4(acc[i][0] + r4.x, acc[i][1] + r4.y, acc[i][2] + r4.z, acc[i][3] + r4.w);
        *(float4*)(C + row * N + n0 + tx * 4) = o;
    }
}

// ======================= Attention: one block per (q-row, head) =======================
__global__ __launch_bounds__(256) void attn_kernel(const float* __restrict__ q,
    const float* __restrict__ k, const float* __restrict__ v, float* __restrict__ attn)
{
    int i = blockIdx.x;     // query row
    int h = blockIdx.y;     // head
    __shared__ float qs[HD];
    __shared__ float sc[S];
    __shared__ float red[256];
    int tid = threadIdx.x;
    if (tid < HD) qs[tid] = q[(size_t)i * D + h * HD + tid] * 0.125f;  // 1/sqrt(64)
    __syncthreads();
    int n = i + 1;  // causal
    // pass 1: scores + max
    float lmax = -1e30f;
    for (int j = tid; j < n; j += 256) {
        const float* kr = k + (size_t)j * D + h * HD;
        float s = 0.0f;
#pragma unroll
        for (int d = 0; d < HD; d += 4) {
            float4 kv = *(const float4*)(kr + d);
            s += qs[d] * kv.x + qs[d + 1] * kv.y + qs[d + 2] * kv.z + qs[d + 3] * kv.w;
        }
        sc[j] = s;
        lmax = fmaxf(lmax, s);
    }
    red[tid] = lmax; __syncthreads();
    for (int st = 128; st > 0; st >>= 1) {
        if (tid < st) red[tid] = fmaxf(red[tid], red[tid + st]);
        __syncthreads();
    }
    float m = red[0];
    __syncthreads();
    // pass 2: exp + sum
    float lsum = 0.0f;
    for (int j = tid; j < n; j += 256) {
        float p = expf(sc[j] - m);
        sc[j] = p;
        lsum += p;
    }
    red[tid] = lsum; __syncthreads();
    for (int st = 128; st > 0; st >>= 1) {
        if (tid < st) red[tid] += red[tid + st];
        __syncthreads();
    }
    float inv = 1.0f / red[0];
    // pass 3: o[d] = sum_j p_j * v[j][d]
    int d = tid & 63, grp = tid >> 6;
    float acc = 0.0f;
    for (int j = grp; j < n; j += 4) acc += sc[j] * v[(size_t)j * D + h * HD + d];
    __syncthreads();
    red[tid] = acc; __syncthreads();
    if (grp == 0) {
        float o = (red[d] + red[64 + d] + red[128 + d] + red[192 + d]) * inv;
        attn[(size_t)i * D + h * HD + d] = o;
    }
}

// ======================= Router (one wave per token) =======================
__global__ __launch_bounds__(64) void router_kernel(const float* __restrict__ x,
    const float* __restrict__ wr, int* __restrict__ ei, float* __restrict__ ew,
    int* __restrict__ counts, float* __restrict__ prob_sums, float* __restrict__ z_sum)
{
    int t = blockIdx.x, lane = threadIdx.x;
    const float* xr = x + (size_t)t * D;
    float p[E] = {};
    for (int d = lane; d < D; d += 64) {
        float xd = xr[d];
        const float* wrow = wr + d * E;
#pragma unroll
        for (int e = 0; e < E; e++) p[e] = fmaf(xd, wrow[e], p[e]);
    }
#pragma unroll
    for (int off = 32; off > 0; off >>= 1) {
#pragma unroll
        for (int e = 0; e < E; e++) p[e] += __shfl_xor(p[e], off);
    }
    // all lanes hold the full 8 logits now
    float m = p[0];
#pragma unroll
    for (int e = 1; e < E; e++) m = fmaxf(m, p[e]);
    float sum = 0.0f, pr[E];
#pragma unroll
    for (int e = 0; e < E; e++) { pr[e] = expf(p[e] - m); sum += pr[e]; }
    float invs = 1.0f / sum;
#pragma unroll
    for (int e = 0; e < E; e++) pr[e] *= invs;
    float lse = m + logf(sum);
    int e1 = 0; float b1 = pr[0];
#pragma unroll
    for (int e = 1; e < E; e++) if (pr[e] > b1) { b1 = pr[e]; e1 = e; }
    int e2 = -1; float b2 = -1.0f;
#pragma unroll
    for (int e = 0; e < E; e++) if (e != e1 && pr[e] > b2) { b2 = pr[e]; e2 = e; }
    float wsum = b1 + b2;
    if (lane == 0) {
        ei[2 * t] = e1; ei[2 * t + 1] = e2;
        ew[2 * t] = b1 / wsum; ew[2 * t + 1] = b2 / wsum;
        atomicAdd(&counts[e1], 1);
        atomicAdd(&counts[e2], 1);
        atomicAdd(z_sum, lse * lse);
    }
    if (lane < E) atomicAdd(&prob_sums[lane], pr[lane]);
}

__global__ void zero_kernel(int* counts, float* prob_sums, float* z_sum)
{
    int tid = threadIdx.x;
    if (tid < E) { counts[tid] = 0; prob_sums[tid] = 0.0f; }
    if (tid == 0) *z_sum = 0.0f;
}

__global__ void finalize_kernel(const int* __restrict__ counts, const float* __restrict__ prob_sums,
    const float* __restrict__ z_sum, int* __restrict__ offs, int* __restrict__ cursor,
    float* __restrict__ aux_out)
{
    if (threadIdx.x == 0) {
        int off = 0;
        for (int e = 0; e < E; e++) { offs[e] = off; cursor[e] = off; off += counts[e]; }
        float z = 1e-3f * (*z_sum) * (1.0f / S);
        float lb = 0.0f;
        for (int e = 0; e < E; e++) lb += ((float)counts[e] / (float)S) * (prob_sums[e] / (float)S);
        lb *= 1e-2f;
        *aux_out = z + lb;
    }
}

__global__ __launch_bounds__(256) void scatter_kernel(const int* __restrict__ ei,
    int* __restrict__ cursor, int* __restrict__ tlist, int* __restrict__ slot_of)
{
    int t = blockIdx.x * 256 + threadIdx.x;
    if (t >= S) return;
#pragma unroll
    for (int kk = 0; kk < 2; kk++) {
        int e = ei[2 * t + kk];
        int slot = atomicAdd(&cursor[e], 1);
        tlist[slot] = t;
        slot_of[2 * t + kk] = slot;
    }
}

// ======================= MoE gate/up fused GEMM (gathered rows) =======================
__global__ __launch_bounds__(256) void moe_gateup(const float* __restrict__ x,
    const float* __restrict__ wg, const float* __restrict__ wu, float* __restrict__ hbuf,
    const int* __restrict__ offs, const int* __restrict__ cnts, const int* __restrict__ tlist)
{
    int e = blockIdx.z;
    int cnt = cnts[e];
    int m0 = blockIdx.y * 64;
    if (m0 >= cnt) return;
    int off = offs[e];
    const float* Bg = wg + (size_t)e * D * F;
    const float* Bu = wu + (size_t)e * D * F;
    __shared__ alignas(16) float As[16][68];
    __shared__ alignas(16) float Gs[16][68];
    __shared__ alignas(16) float Us[16][68];
    int tid = threadIdx.x;
    int tx = tid & 15, ty = tid >> 4;
    int n0 = blockIdx.x * 64;
    int ar = tid >> 2, ak = (tid & 3) * 4;
    const float* Arow = nullptr;
    if (m0 + ar < cnt) Arow = x + (size_t)tlist[off + m0 + ar] * D;
    float accg[4][4] = {}, accu[4][4] = {};
    for (int k0 = 0; k0 < D; k0 += 16) {
        float4 a4 = Arow ? *(const float4*)(Arow + k0 + ak) : make_float4(0, 0, 0, 0);
        float4 g4 = *(const float4*)(Bg + (size_t)(k0 + ty) * F + n0 + tx * 4);
        float4 u4 = *(const float4*)(Bu + (size_t)(k0 + ty) * F + n0 + tx * 4);
        As[ak + 0][ar] = a4.x; As[ak + 1][ar] = a4.y; As[ak + 2][ar] = a4.z; As[ak + 3][ar] = a4.w;
        *(float4*)&Gs[ty][tx * 4] = g4;
        *(float4*)&Us[ty][tx * 4] = u4;
        __syncthreads();
#pragma unroll
        for (int kk = 0; kk < 16; kk++) {
            float4 av = *(const float4*)&As[kk][ty * 4];
            float4 gv = *(const float4*)&Gs[kk][tx * 4];
            float4 uv = *(const float4*)&Us[kk][tx * 4];
            float a_[4] = {av.x, av.y, av.z, av.w};
            float g_[4] = {gv.x, gv.y, gv.z, gv.w};
            float u_[4] = {uv.x, uv.y, uv.z, uv.w};
#pragma unroll
            for (int i = 0; i < 4; i++)
#pragma unroll
                for (int j = 0; j < 4; j++) {
                    accg[i][j] = fmaf(a_[i], g_[j], accg[i][j]);
                    accu[i][j] = fmaf(a_[i], u_[j], accu[i][j]);
                }
        }
        __syncthreads();
    }
#pragma unroll
    for (int i = 0; i < 4; i++) {
        int r = m0 + ty * 4 + i;
        if (r < cnt) {
            float4 o;
            float g, u;
            g = accg[i][0]; u = accu[i][0]; o.x = g / (1.0f + expf(-g)) * u;
            g = accg[i][1]; u = accu[i][1]; o.y = g / (1.0f + expf(-g)) * u;
            g = accg[i][2]; u = accu[i][2]; o.z = g / (1.0f + expf(-g)) * u;
            g = accg[i][3]; u = accu[i][3]; o.w = g / (1.0f + expf(-g)) * u;
            *(float4*)(hbuf + (size_t)(off + r) * F + n0 + tx * 4) = o;
        }
    }
}

// ======================= MoE down GEMM =======================
__global__ __launch_bounds__(256) void moe_down(const float* __restrict__ hbuf,
    const float* __restrict__ wd, float* __restrict__ ybuf,
    const int* __restrict__ offs, const int* __restrict__ cnts)
{
    int e = blockIdx.z;
    int cnt = cnts[e];
    int m0 = blockIdx.y * 64;
    if (m0 >= cnt) return;
    int off = offs[e];
    const float* B = wd + (size_t)e * F * D;
    const int Kd = F, N = D;
    __shared__ alignas(16) float As[16][68];
    __shared__ alignas(16) float Bs[16][68];
    int tid = threadIdx.x;
    int tx = tid & 15, ty = tid >> 4;
    int n0 = blockIdx.x * 64;
    int ar = tid >> 2, ak = (tid & 3) * 4;
    const float* Arow = nullptr;
    if (m0 + ar < cnt) Arow = hbuf + (size_t)(off + m0 + ar) * F;
    float acc[4][4] = {};
    for (int k0 = 0; k0 < Kd; k0 += 16) {
        float4 a4 = Arow ? *(const float4*)(Arow + k0 + ak) : make_float4(0, 0, 0, 0);
        float4 b4 = *(const float4*)(B + (size_t)(k0 + ty) * N + n0 + tx * 4);
        As[ak + 0][ar] = a4.x; As[ak + 1][ar] = a4.y; As[ak + 2][ar] = a4.z; As[ak + 3][ar] = a4.w;
        *(float4*)&Bs[ty][tx * 4] = b4;
        __syncthreads();
#pragma unroll
        for (int kk = 0; kk < 16; kk++) {
            float4 av = *(const float4*)&As[kk][ty * 4];
            float4 bv = *(const float4*)&Bs[kk][tx * 4];
            float a_[4] = {av.x, av.y, av.z, av.w};
            float b_[4] = {bv.x, bv.y, bv.z, bv.w};
#pragma unroll
            for (int i = 0; i < 4; i++)
#pragma unroll
                for (int j = 0; j < 4; j++) acc[i][j] = fmaf(a_[i], b_[j], acc[i][j]);
        }
        __syncthreads();
    }
#pragma unroll
    for (int i = 0; i < 4; i++) {
        int r = m0 + ty * 4 + i;
        if (r < cnt) {
            float4 o = make_float4(acc[i][0], acc[i][1], acc[i][2], acc[i][3]);
            *(float4*)(ybuf + (size_t)(off + r) * N + n0 + tx * 4) = o;
        }
    }
}

// ======================= Combine: out = hs2 + w0*y[slot0] + w1*y[slot1] =======================
__global__ __launch_bounds__(256) void combine_kernel(const float* __restrict__ hs2,
    const float* __restrict__ ybuf, const float* __restrict__ ew,
    const int* __restrict__ slot_of, float* __restrict__ out)
{
    int t = blockIdx.x, tid = threadIdx.x;
    int s0 = slot_of[2 * t], s1 = slot_of[2 * t + 1];
    float w0 = ew[2 * t], w1 = ew[2 * t + 1];
    float4 a = *(const float4*)(hs2 + (size_t)t * D + tid * 4);
    float4 y0 = *(const float4*)(ybuf + (size_t)s0 * D + tid * 4);
    float4 y1 = *(const float4*)(ybuf + (size_t)s1 * D + tid * 4);
    float4 o;
    o.x = a.x + w0 * y0.x + w1 * y1.x;
    o.y = a.y + w0 * y0.y + w1 * y1.y;
    o.z = a.z + w0 * y0.z + w1 * y1.z;
    o.w = a.w + w0 * y0.w + w1 * y1.w;
    *(float4*)(out + (size_t)t * D + tid * 4) = o;
}

// ======================= launch =======================
extern "C" void kernel_launch(void* const* d_in, const int* in_sizes, int n_in,
                              void* d_out, int out_size, void* d_ws, size_t ws_size,
                              hipStream_t stream)
{
    (void)in_sizes; (void)n_in; (void)out_size; (void)ws_size;
    const float* hs   = (const float*)d_in[0];
    // d_in[1] = attention_mask (causal, recomputed implicitly), d_in[2] = position_ids (= arange)
    const float* ln1w = (const float*)d_in[3];
    const float* ln1b = (const float*)d_in[4];
    const float* ln2w = (const float*)d_in[5];
    const float* ln2b = (const float*)d_in[6];
    const float* wq   = (const float*)d_in[7];
    const float* wk   = (const float*)d_in[8];
    const float* wv   = (const float*)d_in[9];
    const float* wo   = (const float*)d_in[10];
    const float* wr   = (const float*)d_in[11];
    const float* wg   = (const float*)d_in[12];
    const float* wu   = (const float*)d_in[13];
    const float* wd   = (const float*)d_in[14];
    float* out = (float*)d_out;

    const size_t TD = (size_t)S * D;   // 2,097,152
    float* wsf   = (float*)d_ws;
    float* xbuf  = wsf;                // [T,D]   x1 then x2
    float* qb    = xbuf + TD;          // [T,D]
    float* kb    = qb + TD;            // [T,D]
    float* vb    = kb + TD;            // [T,D]
    float* attnb = vb + TD;            // [T,D]
    float* hs2   = attnb + TD;         // [T,D]
    float* hbuf  = qb;                 // [4096,F] aliases q/k/v/attn (exactly 4*TD floats)
    float* ybuf  = hs2 + TD;           // [4096,D] = 2*TD floats
    float* ewb       = ybuf + 2 * TD;  // [T,2]
    float* prob_sums = ewb + 2 * S;    // [8]
    float* z_sum     = prob_sums + 8;  // [1] (+pad)
    int* ei      = (int*)(z_sum + 8);  // [T,2]
    int* slot_of = ei + 2 * S;         // [T,2]
    int* tlist   = slot_of + 2 * S;    // [4096]
    int* counts  = tlist + NSLOTS;     // [8]
    int* offs    = counts + 8;         // [8]
    int* cursor  = offs + 8;           // [8]

    // ---- attention sub-block ----
    ln_kernel<<<S, 256, 0, stream>>>(hs, ln1w, ln1b, xbuf);
    gemm_qkv<<<dim3(D / 64, S / 64, 3), 256, 0, stream>>>(xbuf, wq, wk, wv, qb, kb, vb);
    rope_kernel<<<S, 512, 0, stream>>>(qb, kb);
    attn_kernel<<<dim3(S, H), 256, 0, stream>>>(qb, kb, vb, attnb);
    gemm_wo<<<dim3(D / 64, S / 64), 256, 0, stream>>>(attnb, wo, hs, hs2);

    // ---- MoE sub-block ----
    ln_kernel<<<S, 256, 0, stream>>>(hs2, ln2w, ln2b, xbuf);
    zero_kernel<<<1, 64, 0, stream>>>(counts, prob_sums, z_sum);
    router_kernel<<<S, 64, 0, stream>>>(xbuf, wr, ei, ewb, counts, prob_sums, z_sum);
    finalize_kernel<<<1, 64, 0, stream>>>(counts, prob_sums, z_sum, offs, cursor, out + TD);
    scatter_kernel<<<S / 256, 256, 0, stream>>>(ei, cursor, tlist, slot_of);
    moe_gateup<<<dim3(F / 64, NSLOTS / 64, E), 256, 0, stream>>>(xbuf, wg, wu, hbuf, offs, counts, tlist);
    moe_down<<<dim3(D / 64, NSLOTS / 64, E), 256, 0, stream>>>(hbuf, wd, ybuf, offs, counts);
    combine_kernel<<<S, 256, 0, stream>>>(hs2, ybuf, ewb, slot_of, out);
}

// Round 2
// 1536.975 us; speedup vs baseline: 1.9205x; 1.9205x over previous
//
#include <hip/hip_runtime.h>
#include <math.h>

static constexpr int S = 2048;          // tokens (B=1)
static constexpr int D = 1024;          // model dim
static constexpr int H = 16;            // heads
static constexpr int HD = 64;           // head dim
static constexpr int E = 8;             // experts
static constexpr int F = 2048;          // ffn dim
static constexpr int NSLOTS = S * 2;    // 4096 (every token picks exactly 2 experts)

// ======================= LayerNorm =======================
__global__ __launch_bounds__(256) void ln_kernel(const float* __restrict__ x,
    const float* __restrict__ w, const float* __restrict__ b, float* __restrict__ y)
{
    int t = blockIdx.x, tid = threadIdx.x;
    __shared__ float redx[256];
    __shared__ float redy[256];
    const float* xr = x + (size_t)t * D;
    float4 xv = *(const float4*)(xr + tid * 4);
    redx[tid] = xv.x + xv.y + xv.z + xv.w;
    redy[tid] = xv.x * xv.x + xv.y * xv.y + xv.z * xv.z + xv.w * xv.w;
    __syncthreads();
    for (int st = 128; st > 0; st >>= 1) {
        if (tid < st) { redx[tid] += redx[tid + st]; redy[tid] += redy[tid + st]; }
        __syncthreads();
    }
    float mean = redx[0] * (1.0f / D);
    float var  = redy[0] * (1.0f / D) - mean * mean;
    float rstd = rsqrtf(var + 1e-5f);
    float4 wv = *(const float4*)(w + tid * 4);
    float4 bv = *(const float4*)(b + tid * 4);
    float4 o;
    o.x = (xv.x - mean) * rstd * wv.x + bv.x;
    o.y = (xv.y - mean) * rstd * wv.y + bv.y;
    o.z = (xv.z - mean) * rstd * wv.z + bv.z;
    o.w = (xv.w - mean) * rstd * wv.w + bv.w;
    *(float4*)(y + (size_t)t * D + tid * 4) = o;
}

// ======================= RoPE (in-place on q,k) =======================
__global__ __launch_bounds__(512) void rope_kernel(float* __restrict__ q, float* __restrict__ k)
{
    int t = blockIdx.x;
    int idx = threadIdx.x;            // 0..511 = h*32 + i
    int h = idx >> 5, i = idx & 31;
    float invf = powf(10000.0f, -(float)i / 32.0f);
    float ang = (float)t * invf;
    float c = cosf(ang), s = sinf(ang);
    size_t base = (size_t)t * D + h * HD + i;
    float q1 = q[base], q2 = q[base + 32];
    q[base]      = q1 * c - q2 * s;
    q[base + 32] = q2 * c + q1 * s;
    float k1 = k[base], k2 = k[base + 32];
    k[base]      = k1 * c - k2 * s;
    k[base + 32] = k2 * c + k1 * s;
}

// ======================= QKV GEMM (fp32 64x64 tiles, z selects q/k/v) =======================
__global__ __launch_bounds__(256) void gemm_qkv(const float* __restrict__ A,
    const float* __restrict__ wq, const float* __restrict__ wk, const float* __restrict__ wv,
    float* __restrict__ qo, float* __restrict__ ko, float* __restrict__ vo)
{
    const float* B = blockIdx.z == 0 ? wq : (blockIdx.z == 1 ? wk : wv);
    float* C = blockIdx.z == 0 ? qo : (blockIdx.z == 1 ? ko : vo);
    const int Kd = D, N = D;
    __shared__ alignas(16) float As[16][68];
    __shared__ alignas(16) float Bs[16][68];
    int tid = threadIdx.x;
    int tx = tid & 15, ty = tid >> 4;
    int m0 = blockIdx.y * 64, n0 = blockIdx.x * 64;
    int ar = tid >> 2, ak = (tid & 3) * 4;
    float acc[4][4] = {};
    for (int k0 = 0; k0 < Kd; k0 += 16) {
        float4 a4 = *(const float4*)(A + (size_t)(m0 + ar) * Kd + k0 + ak);
        float4 b4 = *(const float4*)(B + (size_t)(k0 + ty) * N + n0 + tx * 4);
        As[ak + 0][ar] = a4.x; As[ak + 1][ar] = a4.y; As[ak + 2][ar] = a4.z; As[ak + 3][ar] = a4.w;
        *(float4*)&Bs[ty][tx * 4] = b4;
        __syncthreads();
#pragma unroll
        for (int kk = 0; kk < 16; kk++) {
            float4 av = *(const float4*)&As[kk][ty * 4];
            float4 bv = *(const float4*)&Bs[kk][tx * 4];
            float a_[4] = {av.x, av.y, av.z, av.w};
            float b_[4] = {bv.x, bv.y, bv.z, bv.w};
#pragma unroll
            for (int i = 0; i < 4; i++)
#pragma unroll
                for (int j = 0; j < 4; j++) acc[i][j] = fmaf(a_[i], b_[j], acc[i][j]);
        }
        __syncthreads();
    }
#pragma unroll
    for (int i = 0; i < 4; i++) {
        float4 o = make_float4(acc[i][0], acc[i][1], acc[i][2], acc[i][3]);
        *(float4*)(C + (size_t)(m0 + ty * 4 + i) * N + n0 + tx * 4) = o;
    }
}

// ======================= O-proj GEMM + residual =======================
__global__ __launch_bounds__(256) void gemm_wo(const float* __restrict__ A,
    const float* __restrict__ B, const float* __restrict__ resid, float* __restrict__ C)
{
    const int Kd = D, N = D;
    __shared__ alignas(16) float As[16][68];
    __shared__ alignas(16) float Bs[16][68];
    int tid = threadIdx.x;
    int tx = tid & 15, ty = tid >> 4;
    int m0 = blockIdx.y * 64, n0 = blockIdx.x * 64;
    int ar = tid >> 2, ak = (tid & 3) * 4;
    float acc[4][4] = {};
    for (int k0 = 0; k0 < Kd; k0 += 16) {
        float4 a4 = *(const float4*)(A + (size_t)(m0 + ar) * Kd + k0 + ak);
        float4 b4 = *(const float4*)(B + (size_t)(k0 + ty) * N + n0 + tx * 4);
        As[ak + 0][ar] = a4.x; As[ak + 1][ar] = a4.y; As[ak + 2][ar] = a4.z; As[ak + 3][ar] = a4.w;
        *(float4*)&Bs[ty][tx * 4] = b4;
        __syncthreads();
#pragma unroll
        for (int kk = 0; kk < 16; kk++) {
            float4 av = *(const float4*)&As[kk][ty * 4];
            float4 bv = *(const float4*)&Bs[kk][tx * 4];
            float a_[4] = {av.x, av.y, av.z, av.w};
            float b_[4] = {bv.x, bv.y, bv.z, bv.w};
#pragma unroll
            for (int i = 0; i < 4; i++)
#pragma unroll
                for (int j = 0; j < 4; j++) acc[i][j] = fmaf(a_[i], b_[j], acc[i][j]);
        }
        __syncthreads();
    }
#pragma unroll
    for (int i = 0; i < 4; i++) {
        size_t row = (size_t)(m0 + ty * 4 + i);
        float4 r4 = *(const float4*)(resid + row * N + n0 + tx * 4);
        float4 o = make_float4(acc[i][0] + r4.x, acc[i][1] + r4.y, acc[i][2] + r4.z, acc[i][3] + r4.w);
        *(float4*)(C + row * N + n0 + tx * 4) = o;
    }
}

// ======================= Flash attention: 64-row q-tiles, paired for balance =======================
// grid = (16 pairs, 16 heads), 256 threads. Block handles q-tiles qt=bx and 31-bx
// => every block does exactly 33 k-tile iterations.
__global__ __launch_bounds__(256) void attn_flash(const float* __restrict__ q,
    const float* __restrict__ k, const float* __restrict__ v, float* __restrict__ attn)
{
    __shared__ alignas(16) float QsT[64][68];   // [d][row], pre-scaled by 1/8
    __shared__ alignas(16) float KsT[64][68];   // [d][col]; reused as Ps[col][row]
    __shared__ alignas(16) float Vs[64][68];    // [row][d]
    const int h = blockIdx.y;
    const int tid = threadIdx.x;
    const int tx = tid & 15, ty = tid >> 4;
    const size_t hoff = (size_t)h * HD;
    const int lrow = tid >> 2;            // 0..63 staging row
    const int lc   = tid & 3;             // chunk-in-row selector

    for (int half = 0; half < 2; half++) {
        const int qt = (half == 0) ? (int)blockIdx.x : 31 - (int)blockIdx.x;
        const int r0 = qt * 64;
        // ---- load Q tile transposed (pre-scaled) ----
#pragma unroll
        for (int l = 0; l < 4; l++) {
            int d0 = lc * 4 + l * 16;
            float4 qv = *(const float4*)(q + (size_t)(r0 + lrow) * D + hoff + d0);
            QsT[d0 + 0][lrow] = qv.x * 0.125f;
            QsT[d0 + 1][lrow] = qv.y * 0.125f;
            QsT[d0 + 2][lrow] = qv.z * 0.125f;
            QsT[d0 + 3][lrow] = qv.w * 0.125f;
        }
        float m_[4], l_[4], o_[4][4];
#pragma unroll
        for (int i = 0; i < 4; i++) {
            m_[i] = -3e38f; l_[i] = 0.0f;
#pragma unroll
            for (int j = 0; j < 4; j++) o_[i][j] = 0.0f;
        }
        __syncthreads();
        for (int kt = 0; kt <= qt; kt++) {
            // ---- stage K (transposed) and V (natural) ----
#pragma unroll
            for (int l = 0; l < 4; l++) {
                int d0 = lc * 4 + l * 16;
                float4 kv = *(const float4*)(k + (size_t)(kt * 64 + lrow) * D + hoff + d0);
                KsT[d0 + 0][lrow] = kv.x; KsT[d0 + 1][lrow] = kv.y;
                KsT[d0 + 2][lrow] = kv.z; KsT[d0 + 3][lrow] = kv.w;
                float4 vv = *(const float4*)(v + (size_t)(kt * 64 + lrow) * D + hoff + d0);
                *(float4*)&Vs[lrow][d0] = vv;
            }
            __syncthreads();
            // ---- S = Q K^T (4x4 per thread) ----
            float s_[4][4] = {};
#pragma unroll 4
            for (int d = 0; d < 64; d++) {
                float4 qv = *(const float4*)&QsT[d][ty * 4];
                float4 kv = *(const float4*)&KsT[d][tx * 4];
                float a_[4] = {qv.x, qv.y, qv.z, qv.w};
                float b_[4] = {kv.x, kv.y, kv.z, kv.w};
#pragma unroll
                for (int i = 0; i < 4; i++)
#pragma unroll
                    for (int j = 0; j < 4; j++) s_[i][j] = fmaf(a_[i], b_[j], s_[i][j]);
            }
            if (kt == qt) {   // causal mask within diagonal tile
#pragma unroll
                for (int i = 0; i < 4; i++)
#pragma unroll
                    for (int j = 0; j < 4; j++)
                        if (tx * 4 + j > ty * 4 + i) s_[i][j] = -1e30f;
            }
            // ---- online softmax update (shuffle over the 16-lane tx group) ----
            float p_[4][4], alpha[4];
#pragma unroll
            for (int i = 0; i < 4; i++) {
                float r = fmaxf(fmaxf(s_[i][0], s_[i][1]), fmaxf(s_[i][2], s_[i][3]));
#pragma unroll
                for (int off = 1; off < 16; off <<= 1) r = fmaxf(r, __shfl_xor(r, off));
                float mn = fmaxf(m_[i], r);
                alpha[i] = expf(m_[i] - mn);
                float rs = 0.0f;
#pragma unroll
                for (int j = 0; j < 4; j++) { p_[i][j] = expf(s_[i][j] - mn); rs += p_[i][j]; }
#pragma unroll
                for (int off = 1; off < 16; off <<= 1) rs += __shfl_xor(rs, off);
                l_[i] = l_[i] * alpha[i] + rs;
                m_[i] = mn;
#pragma unroll
                for (int j = 0; j < 4; j++) o_[i][j] *= alpha[i];
            }
            __syncthreads();   // done reading KsT; safe to overwrite with P
            // ---- write P as Ps[col][row] into KsT ----
#pragma unroll
            for (int i = 0; i < 4; i++)
#pragma unroll
                for (int j = 0; j < 4; j++) KsT[tx * 4 + j][ty * 4 + i] = p_[i][j];
            __syncthreads();
            // ---- O += P V (4x4 per thread) ----
#pragma unroll 4
            for (int j = 0; j < 64; j++) {
                float4 pv = *(const float4*)&KsT[j][ty * 4];
                float4 vv = *(const float4*)&Vs[j][tx * 4];
                float a_[4] = {pv.x, pv.y, pv.z, pv.w};
                float b_[4] = {vv.x, vv.y, vv.z, vv.w};
#pragma unroll
                for (int i = 0; i < 4; i++)
#pragma unroll
                    for (int jj = 0; jj < 4; jj++) o_[i][jj] = fmaf(a_[i], b_[jj], o_[i][jj]);
            }
            __syncthreads();   // before next staging overwrites KsT/Vs
        }
        // ---- epilogue: normalize + store ----
#pragma unroll
        for (int i = 0; i < 4; i++) {
            float inv = 1.0f / l_[i];
            float4 o = make_float4(o_[i][0] * inv, o_[i][1] * inv, o_[i][2] * inv, o_[i][3] * inv);
            *(float4*)(attn + (size_t)(r0 + ty * 4 + i) * D + hoff + tx * 4) = o;
        }
        __syncthreads();   // before next half reloads QsT
    }
}

// ======================= Router (one wave per token) =======================
__global__ __launch_bounds__(64) void router_kernel(const float* __restrict__ x,
    const float* __restrict__ wr, int* __restrict__ ei, float* __restrict__ ew,
    int* __restrict__ counts, float* __restrict__ prob_sums, float* __restrict__ z_sum)
{
    int t = blockIdx.x, lane = threadIdx.x;
    const float* xr = x + (size_t)t * D;
    float p[E] = {};
    for (int d = lane; d < D; d += 64) {
        float xd = xr[d];
        const float* wrow = wr + d * E;
#pragma unroll
        for (int e = 0; e < E; e++) p[e] = fmaf(xd, wrow[e], p[e]);
    }
#pragma unroll
    for (int off = 32; off > 0; off >>= 1) {
#pragma unroll
        for (int e = 0; e < E; e++) p[e] += __shfl_xor(p[e], off);
    }
    float m = p[0];
#pragma unroll
    for (int e = 1; e < E; e++) m = fmaxf(m, p[e]);
    float sum = 0.0f, pr[E];
#pragma unroll
    for (int e = 0; e < E; e++) { pr[e] = expf(p[e] - m); sum += pr[e]; }
    float invs = 1.0f / sum;
#pragma unroll
    for (int e = 0; e < E; e++) pr[e] *= invs;
    float lse = m + logf(sum);
    int e1 = 0; float b1 = pr[0];
#pragma unroll
    for (int e = 1; e < E; e++) if (pr[e] > b1) { b1 = pr[e]; e1 = e; }
    int e2 = -1; float b2 = -1.0f;
#pragma unroll
    for (int e = 0; e < E; e++) if (e != e1 && pr[e] > b2) { b2 = pr[e]; e2 = e; }
    float wsum = b1 + b2;
    if (lane == 0) {
        ei[2 * t] = e1; ei[2 * t + 1] = e2;
        ew[2 * t] = b1 / wsum; ew[2 * t + 1] = b2 / wsum;
        atomicAdd(&counts[e1], 1);
        atomicAdd(&counts[e2], 1);
        atomicAdd(z_sum, lse * lse);
    }
    if (lane < E) atomicAdd(&prob_sums[lane], pr[lane]);
}

__global__ void zero_kernel(int* counts, float* prob_sums, float* z_sum)
{
    int tid = threadIdx.x;
    if (tid < E) { counts[tid] = 0; prob_sums[tid] = 0.0f; }
    if (tid == 0) *z_sum = 0.0f;
}

__global__ void finalize_kernel(const int* __restrict__ counts, const float* __restrict__ prob_sums,
    const float* __restrict__ z_sum, int* __restrict__ offs, int* __restrict__ cursor,
    float* __restrict__ aux_out)
{
    if (threadIdx.x == 0) {
        int off = 0;
        for (int e = 0; e < E; e++) { offs[e] = off; cursor[e] = off; off += counts[e]; }
        float z = 1e-3f * (*z_sum) * (1.0f / S);
        float lb = 0.0f;
        for (int e = 0; e < E; e++) lb += ((float)counts[e] / (float)S) * (prob_sums[e] / (float)S);
        lb *= 1e-2f;
        *aux_out = z + lb;
    }
}

__global__ __launch_bounds__(256) void scatter_kernel(const int* __restrict__ ei,
    int* __restrict__ cursor, int* __restrict__ tlist, int* __restrict__ slot_of)
{
    int t = blockIdx.x * 256 + threadIdx.x;
    if (t >= S) return;
#pragma unroll
    for (int kk = 0; kk < 2; kk++) {
        int e = ei[2 * t + kk];
        int slot = atomicAdd(&cursor[e], 1);
        tlist[slot] = t;
        slot_of[2 * t + kk] = slot;
    }
}

// ======================= MoE gate/up fused GEMM (gathered rows) =======================
__global__ __launch_bounds__(256) void moe_gateup(const float* __restrict__ x,
    const float* __restrict__ wg, const float* __restrict__ wu, float* __restrict__ hbuf,
    const int* __restrict__ offs, const int* __restrict__ cnts, const int* __restrict__ tlist)
{
    int e = blockIdx.z;
    int cnt = cnts[e];
    int m0 = blockIdx.y * 64;
    if (m0 >= cnt) return;
    int off = offs[e];
    const float* Bg = wg + (size_t)e * D * F;
    const float* Bu = wu + (size_t)e * D * F;
    __shared__ alignas(16) float As[16][68];
    __shared__ alignas(16) float Gs[16][68];
    __shared__ alignas(16) float Us[16][68];
    int tid = threadIdx.x;
    int tx = tid & 15, ty = tid >> 4;
    int n0 = blockIdx.x * 64;
    int ar = tid >> 2, ak = (tid & 3) * 4;
    const float* Arow = nullptr;
    if (m0 + ar < cnt) Arow = x + (size_t)tlist[off + m0 + ar] * D;
    float accg[4][4] = {}, accu[4][4] = {};
    for (int k0 = 0; k0 < D; k0 += 16) {
        float4 a4 = Arow ? *(const float4*)(Arow + k0 + ak) : make_float4(0, 0, 0, 0);
        float4 g4 = *(const float4*)(Bg + (size_t)(k0 + ty) * F + n0 + tx * 4);
        float4 u4 = *(const float4*)(Bu + (size_t)(k0 + ty) * F + n0 + tx * 4);
        As[ak + 0][ar] = a4.x; As[ak + 1][ar] = a4.y; As[ak + 2][ar] = a4.z; As[ak + 3][ar] = a4.w;
        *(float4*)&Gs[ty][tx * 4] = g4;
        *(float4*)&Us[ty][tx * 4] = u4;
        __syncthreads();
#pragma unroll
        for (int kk = 0; kk < 16; kk++) {
            float4 av = *(const float4*)&As[kk][ty * 4];
            float4 gv = *(const float4*)&Gs[kk][tx * 4];
            float4 uv = *(const float4*)&Us[kk][tx * 4];
            float a_[4] = {av.x, av.y, av.z, av.w};
            float g_[4] = {gv.x, gv.y, gv.z, gv.w};
            float u_[4] = {uv.x, uv.y, uv.z, uv.w};
#pragma unroll
            for (int i = 0; i < 4; i++)
#pragma unroll
                for (int j = 0; j < 4; j++) {
                    accg[i][j] = fmaf(a_[i], g_[j], accg[i][j]);
                    accu[i][j] = fmaf(a_[i], u_[j], accu[i][j]);
                }
        }
        __syncthreads();
    }
#pragma unroll
    for (int i = 0; i < 4; i++) {
        int r = m0 + ty * 4 + i;
        if (r < cnt) {
            float4 o;
            float g, u;
            g = accg[i][0]; u = accu[i][0]; o.x = g / (1.0f + expf(-g)) * u;
            g = accg[i][1]; u = accu[i][1]; o.y = g / (1.0f + expf(-g)) * u;
            g = accg[i][2]; u = accu[i][2]; o.z = g / (1.0f + expf(-g)) * u;
            g = accg[i][3]; u = accu[i][3]; o.w = g / (1.0f + expf(-g)) * u;
            *(float4*)(hbuf + (size_t)(off + r) * F + n0 + tx * 4) = o;
        }
    }
}

// ======================= MoE down GEMM =======================
__global__ __launch_bounds__(256) void moe_down(const float* __restrict__ hbuf,
    const float* __restrict__ wd, float* __restrict__ ybuf,
    const int* __restrict__ offs, const int* __restrict__ cnts)
{
    int e = blockIdx.z;
    int cnt = cnts[e];
    int m0 = blockIdx.y * 64;
    if (m0 >= cnt) return;
    int off = offs[e];
    const float* B = wd + (size_t)e * F * D;
    const int Kd = F, N = D;
    __shared__ alignas(16) float As[16][68];
    __shared__ alignas(16) float Bs[16][68];
    int tid = threadIdx.x;
    int tx = tid & 15, ty = tid >> 4;
    int n0 = blockIdx.x * 64;
    int ar = tid >> 2, ak = (tid & 3) * 4;
    const float* Arow = nullptr;
    if (m0 + ar < cnt) Arow = hbuf + (size_t)(off + m0 + ar) * F;
    float acc[4][4] = {};
    for (int k0 = 0; k0 < Kd; k0 += 16) {
        float4 a4 = Arow ? *(const float4*)(Arow + k0 + ak) : make_float4(0, 0, 0, 0);
        float4 b4 = *(const float4*)(B + (size_t)(k0 + ty) * N + n0 + tx * 4);
        As[ak + 0][ar] = a4.x; As[ak + 1][ar] = a4.y; As[ak + 2][ar] = a4.z; As[ak + 3][ar] = a4.w;
        *(float4*)&Bs[ty][tx * 4] = b4;
        __syncthreads();
#pragma unroll
        for (int kk = 0; kk < 16; kk++) {
            float4 av = *(const float4*)&As[kk][ty * 4];
            float4 bv = *(const float4*)&Bs[kk][tx * 4];
            float a_[4] = {av.x, av.y, av.z, av.w};
            float b_[4] = {bv.x, bv.y, bv.z, bv.w};
#pragma unroll
            for (int i = 0; i < 4; i++)
#pragma unroll
                for (int j = 0; j < 4; j++) acc[i][j] = fmaf(a_[i], b_[j], acc[i][j]);
        }
        __syncthreads();
    }
#pragma unroll
    for (int i = 0; i < 4; i++) {
        int r = m0 + ty * 4 + i;
        if (r < cnt) {
            float4 o = make_float4(acc[i][0], acc[i][1], acc[i][2], acc[i][3]);
            *(float4*)(ybuf + (size_t)(off + r) * N + n0 + tx * 4) = o;
        }
    }
}

// ======================= Combine: out = hs2 + w0*y[slot0] + w1*y[slot1] =======================
__global__ __launch_bounds__(256) void combine_kernel(const float* __restrict__ hs2,
    const float* __restrict__ ybuf, const float* __restrict__ ew,
    const int* __restrict__ slot_of, float* __restrict__ out)
{
    int t = blockIdx.x, tid = threadIdx.x;
    int s0 = slot_of[2 * t], s1 = slot_of[2 * t + 1];
    float w0 = ew[2 * t], w1 = ew[2 * t + 1];
    float4 a = *(const float4*)(hs2 + (size_t)t * D + tid * 4);
    float4 y0 = *(const float4*)(ybuf + (size_t)s0 * D + tid * 4);
    float4 y1 = *(const float4*)(ybuf + (size_t)s1 * D + tid * 4);
    float4 o;
    o.x = a.x + w0 * y0.x + w1 * y1.x;
    o.y = a.y + w0 * y0.y + w1 * y1.y;
    o.z = a.z + w0 * y0.z + w1 * y1.z;
    o.w = a.w + w0 * y0.w + w1 * y1.w;
    *(float4*)(out + (size_t)t * D + tid * 4) = o;
}

// ======================= launch =======================
extern "C" void kernel_launch(void* const* d_in, const int* in_sizes, int n_in,
                              void* d_out, int out_size, void* d_ws, size_t ws_size,
                              hipStream_t stream)
{
    (void)in_sizes; (void)n_in; (void)out_size; (void)ws_size;
    const float* hs   = (const float*)d_in[0];
    const float* ln1w = (const float*)d_in[3];
    const float* ln1b = (const float*)d_in[4];
    const float* ln2w = (const float*)d_in[5];
    const float* ln2b = (const float*)d_in[6];
    const float* wq   = (const float*)d_in[7];
    const float* wk   = (const float*)d_in[8];
    const float* wv   = (const float*)d_in[9];
    const float* wo   = (const float*)d_in[10];
    const float* wr   = (const float*)d_in[11];
    const float* wg   = (const float*)d_in[12];
    const float* wu   = (const float*)d_in[13];
    const float* wd   = (const float*)d_in[14];
    float* out = (float*)d_out;

    const size_t TD = (size_t)S * D;   // 2,097,152
    float* wsf   = (float*)d_ws;
    float* xbuf  = wsf;                // [T,D]
    float* qb    = xbuf + TD;          // [T,D]
    float* kb    = qb + TD;            // [T,D]
    float* vb    = kb + TD;            // [T,D]
    float* attnb = vb + TD;            // [T,D]
    float* hs2   = attnb + TD;         // [T,D]
    float* hbuf  = qb;                 // [4096,F] aliases q/k/v/attn
    float* ybuf  = hs2 + TD;           // [4096,D]
    float* ewb       = ybuf + 2 * TD;  // [T,2]
    float* prob_sums = ewb + 2 * S;    // [8]
    float* z_sum     = prob_sums + 8;  // [1] (+pad)
    int* ei      = (int*)(z_sum + 8);  // [T,2]
    int* slot_of = ei + 2 * S;         // [T,2]
    int* tlist   = slot_of + 2 * S;    // [4096]
    int* counts  = tlist + NSLOTS;     // [8]
    int* offs    = counts + 8;         // [8]
    int* cursor  = offs + 8;           // [8]

    // ---- attention sub-block ----
    ln_kernel<<<S, 256, 0, stream>>>(hs, ln1w, ln1b, xbuf);
    gemm_qkv<<<dim3(D / 64, S / 64, 3), 256, 0, stream>>>(xbuf, wq, wk, wv, qb, kb, vb);
    rope_kernel<<<S, 512, 0, stream>>>(qb, kb);
    attn_flash<<<dim3(16, H), 256, 0, stream>>>(qb, kb, vb, attnb);
    gemm_wo<<<dim3(D / 64, S / 64), 256, 0, stream>>>(attnb, wo, hs, hs2);

    // ---- MoE sub-block ----
    ln_kernel<<<S, 256, 0, stream>>>(hs2, ln2w, ln2b, xbuf);
    zero_kernel<<<1, 64, 0, stream>>>(counts, prob_sums, z_sum);
    router_kernel<<<S, 64, 0, stream>>>(xbuf, wr, ei, ewb, counts, prob_sums, z_sum);
    finalize_kernel<<<1, 64, 0, stream>>>(counts, prob_sums, z_sum, offs, cursor, out + TD);
    scatter_kernel<<<S / 256, 256, 0, stream>>>(ei, cursor, tlist, slot_of);
    moe_gateup<<<dim3(F / 64, NSLOTS / 64, E), 256, 0, stream>>>(xbuf, wg, wu, hbuf, offs, counts, tlist);
    moe_down<<<dim3(D / 64, NSLOTS / 64, E), 256, 0, stream>>>(hbuf, wd, ybuf, offs, counts);
    combine_kernel<<<S, 256, 0, stream>>>(hs2, ybuf, ewb, slot_of, out);
}

// Round 4
// 1096.926 us; speedup vs baseline: 2.6910x; 1.4012x over previous
//
#include <hip/hip_runtime.h>
#include <math.h>

static constexpr int S = 2048;          // tokens (B=1)
static constexpr int D = 1024;          // model dim
static constexpr int H = 16;            // heads
static constexpr int HD = 64;           // head dim
static constexpr int E = 8;             // experts
static constexpr int F = 2048;          // ffn dim
static constexpr int NSLOTS = S * 2;    // 4096
static constexpr int NPAD = NSLOTS + 128;  // padded slot rows

typedef __attribute__((ext_vector_type(8))) short bf16x8;
typedef __attribute__((ext_vector_type(4))) float f32x4;

__device__ __forceinline__ float bf2f(ushort u) {
    uint32_t x = ((uint32_t)u) << 16; float f; __builtin_memcpy(&f, &x, 4); return f;
}
__device__ __forceinline__ ushort f2bf(float f) {
    uint32_t x; __builtin_memcpy(&x, &f, 4);
    return (ushort)((x + 0x7fffu + ((x >> 16) & 1u)) >> 16);
}
__device__ __forceinline__ void async_copy16(const void* gptr, void* ldsptr) {
    __builtin_amdgcn_global_load_lds(
        (const __attribute__((address_space(1))) void*)gptr,
        (__attribute__((address_space(3))) void*)ldsptr, 16, 0, 0);
}

// ======================= cast + transpose fp32 [K][N] -> bf16 [N][K] =======================
__global__ __launch_bounds__(256) void castT_kernel(const float* __restrict__ src,
    ushort* __restrict__ dst, int K, int N)
{
    __shared__ float T[64][65];
    int z = blockIdx.z;
    src += (size_t)z * K * N; dst += (size_t)z * K * N;
    int k0 = blockIdx.y * 64, n0 = blockIdx.x * 64;
    int t = threadIdx.x;
    int r = t >> 4, c4 = (t & 15) * 4;
#pragma unroll
    for (int it = 0; it < 4; it++) {
        float4 v = *(const float4*)(src + (size_t)(k0 + r + it * 16) * N + n0 + c4);
        T[r + it * 16][c4 + 0] = v.x; T[r + it * 16][c4 + 1] = v.y;
        T[r + it * 16][c4 + 2] = v.z; T[r + it * 16][c4 + 3] = v.w;
    }
    __syncthreads();
#pragma unroll
    for (int it = 0; it < 4; it++) {
        int rr = r + it * 16;   // n-local
        ushort4 o;
        o.x = f2bf(T[c4 + 0][rr]); o.y = f2bf(T[c4 + 1][rr]);
        o.z = f2bf(T[c4 + 2][rr]); o.w = f2bf(T[c4 + 3][rr]);
        *(ushort4*)(dst + (size_t)(n0 + rr) * K + k0 + c4) = o;
    }
}

// ======================= LayerNorm: fp32 out + optional bf16 out =======================
__global__ __launch_bounds__(256) void ln_kernel(const float* __restrict__ x,
    const float* __restrict__ w, const float* __restrict__ b,
    float* __restrict__ yf, ushort* __restrict__ ybf)
{
    int t = blockIdx.x, tid = threadIdx.x;
    __shared__ float redx[256];
    __shared__ float redy[256];
    const float* xr = x + (size_t)t * D;
    float4 xv = *(const float4*)(xr + tid * 4);
    redx[tid] = xv.x + xv.y + xv.z + xv.w;
    redy[tid] = xv.x * xv.x + xv.y * xv.y + xv.z * xv.z + xv.w * xv.w;
    __syncthreads();
    for (int st = 128; st > 0; st >>= 1) {
        if (tid < st) { redx[tid] += redx[tid + st]; redy[tid] += redy[tid + st]; }
        __syncthreads();
    }
    float mean = redx[0] * (1.0f / D);
    float var  = redy[0] * (1.0f / D) - mean * mean;
    float rstd = rsqrtf(var + 1e-5f);
    float4 wv = *(const float4*)(w + tid * 4);
    float4 bv = *(const float4*)(b + tid * 4);
    float4 o;
    o.x = (xv.x - mean) * rstd * wv.x + bv.x;
    o.y = (xv.y - mean) * rstd * wv.y + bv.y;
    o.z = (xv.z - mean) * rstd * wv.z + bv.z;
    o.w = (xv.w - mean) * rstd * wv.w + bv.w;
    *(float4*)(yf + (size_t)t * D + tid * 4) = o;
    if (ybf) {
        ushort4 ob; ob.x = f2bf(o.x); ob.y = f2bf(o.y); ob.z = f2bf(o.z); ob.w = f2bf(o.w);
        *(ushort4*)(ybf + (size_t)t * D + tid * 4) = ob;
    }
}

// ======================= RoPE (in-place on fp32 q,k) =======================
__global__ __launch_bounds__(512) void rope_kernel(float* __restrict__ q, float* __restrict__ k)
{
    int t = blockIdx.x;
    int idx = threadIdx.x;
    int h = idx >> 5, i = idx & 31;
    float invf = powf(10000.0f, -(float)i / 32.0f);
    float ang = (float)t * invf;
    float c = cosf(ang), s = sinf(ang);
    size_t base = (size_t)t * D + h * HD + i;
    float q1 = q[base], q2 = q[base + 32];
    q[base]      = q1 * c - q2 * s;
    q[base + 32] = q2 * c + q1 * s;
    float k1 = k[base], k2 = k[base + 32];
    k[base]      = k1 * c - k2 * s;
    k[base + 32] = k2 * c + k1 * s;
}

// ======================= QKV GEMM (fp32 64x64 tiles) =======================
__global__ __launch_bounds__(256) void gemm_qkv(const float* __restrict__ A,
    const float* __restrict__ wq, const float* __restrict__ wk, const float* __restrict__ wv,
    float* __restrict__ qo, float* __restrict__ ko, float* __restrict__ vo)
{
    const float* B = blockIdx.z == 0 ? wq : (blockIdx.z == 1 ? wk : wv);
    float* C = blockIdx.z == 0 ? qo : (blockIdx.z == 1 ? ko : vo);
    const int Kd = D, N = D;
    __shared__ alignas(16) float As[16][68];
    __shared__ alignas(16) float Bs[16][68];
    int tid = threadIdx.x;
    int tx = tid & 15, ty = tid >> 4;
    int m0 = blockIdx.y * 64, n0 = blockIdx.x * 64;
    int ar = tid >> 2, ak = (tid & 3) * 4;
    float acc[4][4] = {};
    for (int k0 = 0; k0 < Kd; k0 += 16) {
        float4 a4 = *(const float4*)(A + (size_t)(m0 + ar) * Kd + k0 + ak);
        float4 b4 = *(const float4*)(B + (size_t)(k0 + ty) * N + n0 + tx * 4);
        As[ak + 0][ar] = a4.x; As[ak + 1][ar] = a4.y; As[ak + 2][ar] = a4.z; As[ak + 3][ar] = a4.w;
        *(float4*)&Bs[ty][tx * 4] = b4;
        __syncthreads();
#pragma unroll
        for (int kk = 0; kk < 16; kk++) {
            float4 av = *(const float4*)&As[kk][ty * 4];
            float4 bv = *(const float4*)&Bs[kk][tx * 4];
            float a_[4] = {av.x, av.y, av.z, av.w};
            float b_[4] = {bv.x, bv.y, bv.z, bv.w};
#pragma unroll
            for (int i = 0; i < 4; i++)
#pragma unroll
                for (int j = 0; j < 4; j++) acc[i][j] = fmaf(a_[i], b_[j], acc[i][j]);
        }
        __syncthreads();
    }
#pragma unroll
    for (int i = 0; i < 4; i++) {
        float4 o = make_float4(acc[i][0], acc[i][1], acc[i][2], acc[i][3]);
        *(float4*)(C + (size_t)(m0 + ty * 4 + i) * N + n0 + tx * 4) = o;
    }
}

// ======================= O-proj GEMM + residual (fp32) =======================
__global__ __launch_bounds__(256) void gemm_wo(const float* __restrict__ A,
    const float* __restrict__ B, const float* __restrict__ resid, float* __restrict__ C)
{
    const int Kd = D, N = D;
    __shared__ alignas(16) float As[16][68];
    __shared__ alignas(16) float Bs[16][68];
    int tid = threadIdx.x;
    int tx = tid & 15, ty = tid >> 4;
    int m0 = blockIdx.y * 64, n0 = blockIdx.x * 64;
    int ar = tid >> 2, ak = (tid & 3) * 4;
    float acc[4][4] = {};
    for (int k0 = 0; k0 < Kd; k0 += 16) {
        float4 a4 = *(const float4*)(A + (size_t)(m0 + ar) * Kd + k0 + ak);
        float4 b4 = *(const float4*)(B + (size_t)(k0 + ty) * N + n0 + tx * 4);
        As[ak + 0][ar] = a4.x; As[ak + 1][ar] = a4.y; As[ak + 2][ar] = a4.z; As[ak + 3][ar] = a4.w;
        *(float4*)&Bs[ty][tx * 4] = b4;
        __syncthreads();
#pragma unroll
        for (int kk = 0; kk < 16; kk++) {
            float4 av = *(const float4*)&As[kk][ty * 4];
            float4 bv = *(const float4*)&Bs[kk][tx * 4];
            float a_[4] = {av.x, av.y, av.z, av.w};
            float b_[4] = {bv.x, bv.y, bv.z, bv.w};
#pragma unroll
            for (int i = 0; i < 4; i++)
#pragma unroll
                for (int j = 0; j < 4; j++) acc[i][j] = fmaf(a_[i], b_[j], acc[i][j]);
        }
        __syncthreads();
    }
#pragma unroll
    for (int i = 0; i < 4; i++) {
        size_t row = (size_t)(m0 + ty * 4 + i);
        float4 r4 = *(const float4*)(resid + row * N + n0 + tx * 4);
        float4 o = make_float4(acc[i][0] + r4.x, acc[i][1] + r4.y, acc[i][2] + r4.z, acc[i][3] + r4.w);
        *(float4*)(C + row * N + n0 + tx * 4) = o;
    }
}

// ======================= Flash attention (fp32, paired q-tiles) =======================
__global__ __launch_bounds__(256) void attn_flash(const float* __restrict__ q,
    const float* __restrict__ k, const float* __restrict__ v, float* __restrict__ attn)
{
    __shared__ alignas(16) float QsT[64][68];
    __shared__ alignas(16) float KsT[64][68];
    __shared__ alignas(16) float Vs[64][68];
    const int h = blockIdx.y;
    const int tid = threadIdx.x;
    const int tx = tid & 15, ty = tid >> 4;
    const size_t hoff = (size_t)h * HD;
    const int lrow = tid >> 2;
    const int lc   = tid & 3;

    for (int half = 0; half < 2; half++) {
        const int qt = (half == 0) ? (int)blockIdx.x : 31 - (int)blockIdx.x;
        const int r0 = qt * 64;
#pragma unroll
        for (int l = 0; l < 4; l++) {
            int d0 = lc * 4 + l * 16;
            float4 qv = *(const float4*)(q + (size_t)(r0 + lrow) * D + hoff + d0);
            QsT[d0 + 0][lrow] = qv.x * 0.125f;
            QsT[d0 + 1][lrow] = qv.y * 0.125f;
            QsT[d0 + 2][lrow] = qv.z * 0.125f;
            QsT[d0 + 3][lrow] = qv.w * 0.125f;
        }
        float m_[4], l_[4], o_[4][4];
#pragma unroll
        for (int i = 0; i < 4; i++) {
            m_[i] = -3e38f; l_[i] = 0.0f;
#pragma unroll
            for (int j = 0; j < 4; j++) o_[i][j] = 0.0f;
        }
        __syncthreads();
        for (int kt = 0; kt <= qt; kt++) {
#pragma unroll
            for (int l = 0; l < 4; l++) {
                int d0 = lc * 4 + l * 16;
                float4 kv = *(const float4*)(k + (size_t)(kt * 64 + lrow) * D + hoff + d0);
                KsT[d0 + 0][lrow] = kv.x; KsT[d0 + 1][lrow] = kv.y;
                KsT[d0 + 2][lrow] = kv.z; KsT[d0 + 3][lrow] = kv.w;
                float4 vv = *(const float4*)(v + (size_t)(kt * 64 + lrow) * D + hoff + d0);
                *(float4*)&Vs[lrow][d0] = vv;
            }
            __syncthreads();
            float s_[4][4] = {};
#pragma unroll 4
            for (int d = 0; d < 64; d++) {
                float4 qv = *(const float4*)&QsT[d][ty * 4];
                float4 kv = *(const float4*)&KsT[d][tx * 4];
                float a_[4] = {qv.x, qv.y, qv.z, qv.w};
                float b_[4] = {kv.x, kv.y, kv.z, kv.w};
#pragma unroll
                for (int i = 0; i < 4; i++)
#pragma unroll
                    for (int j = 0; j < 4; j++) s_[i][j] = fmaf(a_[i], b_[j], s_[i][j]);
            }
            if (kt == qt) {
#pragma unroll
                for (int i = 0; i < 4; i++)
#pragma unroll
                    for (int j = 0; j < 4; j++)
                        if (tx * 4 + j > ty * 4 + i) s_[i][j] = -1e30f;
            }
            float p_[4][4], alpha[4];
#pragma unroll
            for (int i = 0; i < 4; i++) {
                float r = fmaxf(fmaxf(s_[i][0], s_[i][1]), fmaxf(s_[i][2], s_[i][3]));
#pragma unroll
                for (int off = 1; off < 16; off <<= 1) r = fmaxf(r, __shfl_xor(r, off));
                float mn = fmaxf(m_[i], r);
                alpha[i] = expf(m_[i] - mn);
                float rs = 0.0f;
#pragma unroll
                for (int j = 0; j < 4; j++) { p_[i][j] = expf(s_[i][j] - mn); rs += p_[i][j]; }
#pragma unroll
                for (int off = 1; off < 16; off <<= 1) rs += __shfl_xor(rs, off);
                l_[i] = l_[i] * alpha[i] + rs;
                m_[i] = mn;
#pragma unroll
                for (int j = 0; j < 4; j++) o_[i][j] *= alpha[i];
            }
            __syncthreads();
#pragma unroll
            for (int i = 0; i < 4; i++)
#pragma unroll
                for (int j = 0; j < 4; j++) KsT[tx * 4 + j][ty * 4 + i] = p_[i][j];
            __syncthreads();
#pragma unroll 4
            for (int j = 0; j < 64; j++) {
                float4 pv = *(const float4*)&KsT[j][ty * 4];
                float4 vv = *(const float4*)&Vs[j][tx * 4];
                float a_[4] = {pv.x, pv.y, pv.z, pv.w};
                float b_[4] = {vv.x, vv.y, vv.z, vv.w};
#pragma unroll
                for (int i = 0; i < 4; i++)
#pragma unroll
                    for (int jj = 0; jj < 4; jj++) o_[i][jj] = fmaf(a_[i], b_[jj], o_[i][jj]);
            }
            __syncthreads();
        }
#pragma unroll
        for (int i = 0; i < 4; i++) {
            float inv = 1.0f / l_[i];
            float4 o = make_float4(o_[i][0] * inv, o_[i][1] * inv, o_[i][2] * inv, o_[i][3] * inv);
            *(float4*)(attn + (size_t)(r0 + ty * 4 + i) * D + hoff + tx * 4) = o;
        }
        __syncthreads();
    }
}

// ======================= Router (fp32 input — routing must match reference exactly) ==========
__global__ __launch_bounds__(64) void router_kernel(const float* __restrict__ x,
    const float* __restrict__ wr, int* __restrict__ ei, float* __restrict__ ew,
    int* __restrict__ counts, float* __restrict__ prob_sums, float* __restrict__ z_sum)
{
    int t = blockIdx.x, lane = threadIdx.x;
    const float* xr = x + (size_t)t * D;
    float p[E] = {};
    for (int d = lane; d < D; d += 64) {
        float xd = xr[d];
        const float* wrow = wr + d * E;
#pragma unroll
        for (int e = 0; e < E; e++) p[e] = fmaf(xd, wrow[e], p[e]);
    }
#pragma unroll
    for (int off = 32; off > 0; off >>= 1) {
#pragma unroll
        for (int e = 0; e < E; e++) p[e] += __shfl_xor(p[e], off);
    }
    float m = p[0];
#pragma unroll
    for (int e = 1; e < E; e++) m = fmaxf(m, p[e]);
    float sum = 0.0f, pr[E];
#pragma unroll
    for (int e = 0; e < E; e++) { pr[e] = expf(p[e] - m); sum += pr[e]; }
    float invs = 1.0f / sum;
#pragma unroll
    for (int e = 0; e < E; e++) pr[e] *= invs;
    float lse = m + logf(sum);
    int e1 = 0; float b1 = pr[0];
#pragma unroll
    for (int e = 1; e < E; e++) if (pr[e] > b1) { b1 = pr[e]; e1 = e; }
    int e2 = -1; float b2 = -1.0f;
#pragma unroll
    for (int e = 0; e < E; e++) if (e != e1 && pr[e] > b2) { b2 = pr[e]; e2 = e; }
    float wsum = b1 + b2;
    if (lane == 0) {
        ei[2 * t] = e1; ei[2 * t + 1] = e2;
        ew[2 * t] = b1 / wsum; ew[2 * t + 1] = b2 / wsum;
        atomicAdd(&counts[e1], 1);
        atomicAdd(&counts[e2], 1);
        atomicAdd(z_sum, lse * lse);
    }
    if (lane < E) atomicAdd(&prob_sums[lane], pr[lane]);
}

__global__ void zero_kernel(int* counts, float* prob_sums, float* z_sum)
{
    int tid = threadIdx.x;
    if (tid < E) { counts[tid] = 0; prob_sums[tid] = 0.0f; }
    if (tid == 0) *z_sum = 0.0f;
}

__global__ void finalize_kernel(const int* __restrict__ counts, const float* __restrict__ prob_sums,
    const float* __restrict__ z_sum, int* __restrict__ offs, int* __restrict__ cursor,
    float* __restrict__ aux_out)
{
    if (threadIdx.x == 0) {
        int off = 0;
        for (int e = 0; e < E; e++) { offs[e] = off; cursor[e] = off; off += counts[e]; }
        float z = 1e-3f * (*z_sum) * (1.0f / S);
        float lb = 0.0f;
        for (int e = 0; e < E; e++) lb += ((float)counts[e] / (float)S) * (prob_sums[e] / (float)S);
        lb *= 1e-2f;
        *aux_out = z + lb;
    }
}

__global__ __launch_bounds__(256) void scatter_kernel(const int* __restrict__ ei,
    int* __restrict__ cursor, int* __restrict__ tlist, int* __restrict__ slot_of)
{
    int t = blockIdx.x * 256 + threadIdx.x;
    if (t >= S) return;
#pragma unroll
    for (int kk = 0; kk < 2; kk++) {
        int e = ei[2 * t + kk];
        int slot = atomicAdd(&cursor[e], 1);
        tlist[slot] = t;
        slot_of[2 * t + kk] = slot;
    }
}

// ======================= gather tokens into slot order (bf16) =======================
__global__ __launch_bounds__(256) void gather_kernel(const ushort* __restrict__ xbf,
    const int* __restrict__ tlist, ushort* __restrict__ xg)
{
    int slot = blockIdx.x;
    int t4 = threadIdx.x * 4;
    ushort4 vv;
    if (slot < NSLOTS) {
        int tok = tlist[slot];
        vv = *(const ushort4*)(xbf + (size_t)tok * D + t4);
    } else {
        vv = make_ushort4(0, 0, 0, 0);
    }
    *(ushort4*)(xg + (size_t)slot * D + t4) = vv;
}

// ======================= MoE fused gate+up MFMA GEMM + SiLU epilogue =======================
// 128x128 tile, BK=64, LDS chunk-major [kc][row] (global_load_lds-friendly).
__global__ __launch_bounds__(256) void moe_gateup_mfma(const ushort* __restrict__ xg,
    const ushort* __restrict__ wgt, const ushort* __restrict__ wut,
    ushort* __restrict__ Hb, const int* __restrict__ offs, const int* __restrict__ cnts)
{
    int e = blockIdx.z;
    int cnt = cnts[e];
    int m0 = blockIdx.y * 128;
    if (m0 >= cnt) return;
    int off = offs[e];
    const ushort* Gt = wgt + (size_t)e * F * D;   // [F][D]
    const ushort* Ut = wut + (size_t)e * F * D;
    int n0 = blockIdx.x * 128;
    __shared__ ushort As[8192], Gs[8192], Us[8192];
    const int tid = threadIdx.x;
    const int w = tid >> 6, l = tid & 63;
    const int wm = (w >> 1) * 64, wn = (w & 1) * 64;
    const ushort* Arow = xg + (size_t)(off + m0) * D;
    const ushort* Grow = Gt + (size_t)n0 * D;
    const ushort* Urow = Ut + (size_t)n0 * D;
    f32x4 accg[4][4], accu[4][4];
#pragma unroll
    for (int i = 0; i < 4; i++)
#pragma unroll
        for (int j = 0; j < 4; j++) { accg[i][j] = (f32x4){0.f,0.f,0.f,0.f}; accu[i][j] = (f32x4){0.f,0.f,0.f,0.f}; }
    for (int k0 = 0; k0 < D; k0 += 64) {
#pragma unroll
        for (int it = 0; it < 4; it++) {
            int c = it * 256 + tid;
            int kc = c >> 7, r = c & 127;
            async_copy16(Arow + (size_t)r * D + k0 + kc * 8, As + (size_t)(it * 256 + w * 64) * 8);
            async_copy16(Grow + (size_t)r * D + k0 + kc * 8, Gs + (size_t)(it * 256 + w * 64) * 8);
            async_copy16(Urow + (size_t)r * D + k0 + kc * 8, Us + (size_t)(it * 256 + w * 64) * 8);
        }
        __syncthreads();
#pragma unroll
        for (int hh = 0; hh < 2; hh++) {
            bf16x8 af[4], gf[4], uf[4];
            int kc = hh * 4 + (l >> 4);
#pragma unroll
            for (int f = 0; f < 4; f++) {
                af[f] = *(const bf16x8*)(As + (size_t)(kc * 128 + wm + f * 16 + (l & 15)) * 8);
                gf[f] = *(const bf16x8*)(Gs + (size_t)(kc * 128 + wn + f * 16 + (l & 15)) * 8);
                uf[f] = *(const bf16x8*)(Us + (size_t)(kc * 128 + wn + f * 16 + (l & 15)) * 8);
            }
#pragma unroll
            for (int fm = 0; fm < 4; fm++)
#pragma unroll
                for (int fn = 0; fn < 4; fn++) {
                    accg[fm][fn] = __builtin_amdgcn_mfma_f32_16x16x32_bf16(af[fm], gf[fn], accg[fm][fn], 0, 0, 0);
                    accu[fm][fn] = __builtin_amdgcn_mfma_f32_16x16x32_bf16(af[fm], uf[fn], accu[fm][fn], 0, 0, 0);
                }
        }
        __syncthreads();
    }
#pragma unroll
    for (int fm = 0; fm < 4; fm++)
#pragma unroll
        for (int fn = 0; fn < 4; fn++)
#pragma unroll
            for (int r = 0; r < 4; r++) {
                int rloc = m0 + wm + fm * 16 + (l >> 4) * 4 + r;
                if (rloc < cnt) {
                    int col = n0 + wn + fn * 16 + (l & 15);
                    float g = accg[fm][fn][r], u = accu[fm][fn][r];
                    Hb[(size_t)(off + rloc) * F + col] = f2bf(g / (1.0f + expf(-g)) * u);
                }
            }
}

// ======================= MoE down MFMA GEMM =======================
__global__ __launch_bounds__(256) void moe_down_mfma(const ushort* __restrict__ Hb,
    const ushort* __restrict__ wdt, ushort* __restrict__ yb,
    const int* __restrict__ offs, const int* __restrict__ cnts)
{
    int e = blockIdx.z;
    int cnt = cnts[e];
    int m0 = blockIdx.y * 128;
    if (m0 >= cnt) return;
    int off = offs[e];
    const ushort* Bt = wdt + (size_t)e * D * F;    // [D][F]
    int n0 = blockIdx.x * 128;
    __shared__ ushort As[8192], Bs[8192];
    const int tid = threadIdx.x;
    const int w = tid >> 6, l = tid & 63;
    const int wm = (w >> 1) * 64, wn = (w & 1) * 64;
    const ushort* Arow = Hb + (size_t)(off + m0) * F;
    const ushort* Brow = Bt + (size_t)n0 * F;
    f32x4 acc[4][4];
#pragma unroll
    for (int i = 0; i < 4; i++)
#pragma unroll
        for (int j = 0; j < 4; j++) acc[i][j] = (f32x4){0.f,0.f,0.f,0.f};
    for (int k0 = 0; k0 < F; k0 += 64) {
#pragma unroll
        for (int it = 0; it < 4; it++) {
            int c = it * 256 + tid;
            int kc = c >> 7, r = c & 127;
            async_copy16(Arow + (size_t)r * F + k0 + kc * 8, As + (size_t)(it * 256 + w * 64) * 8);
            async_copy16(Brow + (size_t)r * F + k0 + kc * 8, Bs + (size_t)(it * 256 + w * 64) * 8);
        }
        __syncthreads();
#pragma unroll
        for (int hh = 0; hh < 2; hh++) {
            bf16x8 af[4], bfr[4];
            int kc = hh * 4 + (l >> 4);
#pragma unroll
            for (int f = 0; f < 4; f++) {
                af[f]  = *(const bf16x8*)(As + (size_t)(kc * 128 + wm + f * 16 + (l & 15)) * 8);
                bfr[f] = *(const bf16x8*)(Bs + (size_t)(kc * 128 + wn + f * 16 + (l & 15)) * 8);
            }
#pragma unroll
            for (int fm = 0; fm < 4; fm++)
#pragma unroll
                for (int fn = 0; fn < 4; fn++)
                    acc[fm][fn] = __builtin_amdgcn_mfma_f32_16x16x32_bf16(af[fm], bfr[fn], acc[fm][fn], 0, 0, 0);
        }
        __syncthreads();
    }
#pragma unroll
    for (int fm = 0; fm < 4; fm++)
#pragma unroll
        for (int fn = 0; fn < 4; fn++)
#pragma unroll
            for (int r = 0; r < 4; r++) {
                int rloc = m0 + wm + fm * 16 + (l >> 4) * 4 + r;
                if (rloc < cnt) {
                    int col = n0 + wn + fn * 16 + (l & 15);
                    yb[(size_t)(off + rloc) * D + col] = f2bf(acc[fm][fn][r]);
                }
            }
}

// ======================= Combine: out = hs2 + w0*y[slot0] + w1*y[slot1] =======================
__global__ __launch_bounds__(256) void combine_kernel(const float* __restrict__ hs2,
    const ushort* __restrict__ yb, const float* __restrict__ ew,
    const int* __restrict__ slot_of, float* __restrict__ out)
{
    int t = blockIdx.x, tid = threadIdx.x;
    int s0 = slot_of[2 * t], s1 = slot_of[2 * t + 1];
    float w0 = ew[2 * t], w1 = ew[2 * t + 1];
    float4 a = *(const float4*)(hs2 + (size_t)t * D + tid * 4);
    ushort4 y0 = *(const ushort4*)(yb + (size_t)s0 * D + tid * 4);
    ushort4 y1 = *(const ushort4*)(yb + (size_t)s1 * D + tid * 4);
    float4 o;
    o.x = a.x + w0 * bf2f(y0.x) + w1 * bf2f(y1.x);
    o.y = a.y + w0 * bf2f(y0.y) + w1 * bf2f(y1.y);
    o.z = a.z + w0 * bf2f(y0.z) + w1 * bf2f(y1.z);
    o.w = a.w + w0 * bf2f(y0.w) + w1 * bf2f(y1.w);
    *(float4*)(out + (size_t)t * D + tid * 4) = o;
}

// ======================= launch =======================
extern "C" void kernel_launch(void* const* d_in, const int* in_sizes, int n_in,
                              void* d_out, int out_size, void* d_ws, size_t ws_size,
                              hipStream_t stream)
{
    (void)in_sizes; (void)n_in; (void)out_size; (void)ws_size;
    const float* hs   = (const float*)d_in[0];
    const float* ln1w = (const float*)d_in[3];
    const float* ln1b = (const float*)d_in[4];
    const float* ln2w = (const float*)d_in[5];
    const float* ln2b = (const float*)d_in[6];
    const float* wq   = (const float*)d_in[7];
    const float* wk   = (const float*)d_in[8];
    const float* wv   = (const float*)d_in[9];
    const float* wo   = (const float*)d_in[10];
    const float* wr   = (const float*)d_in[11];
    const float* wg   = (const float*)d_in[12];
    const float* wu   = (const float*)d_in[13];
    const float* wd   = (const float*)d_in[14];
    float* out = (float*)d_out;

    const size_t TD = (size_t)S * D;
    char* p = (char*)d_ws;
    auto alloc = [&](size_t bytes) { char* r = p; p += (bytes + 255) & ~(size_t)255; return r; };

    ushort* wgt  = (ushort*)alloc((size_t)E * D * F * 2);
    ushort* wut  = (ushort*)alloc((size_t)E * D * F * 2);
    ushort* wdt  = (ushort*)alloc((size_t)E * D * F * 2);
    float*  xbuf = (float*)alloc(TD * 4);
    float*  qb   = (float*)alloc(TD * 4);
    float*  kb   = (float*)alloc(TD * 4);
    float*  vb   = (float*)alloc(TD * 4);
    float*  attnb= (float*)alloc(TD * 4);
    float*  hs2  = (float*)alloc(TD * 4);
    float*  xf32 = (float*)alloc(TD * 4);
    ushort* xbf  = (ushort*)alloc(TD * 2);
    ushort* xg   = (ushort*)alloc((size_t)NPAD * D * 2);
    ushort* Hb   = (ushort*)alloc((size_t)NPAD * F * 2);
    ushort* yb   = (ushort*)alloc((size_t)NPAD * D * 2);
    float*  ewb       = (float*)alloc(2 * S * 4);
    float*  prob_sums = (float*)alloc(8 * 4);
    float*  z_sum     = (float*)alloc(8 * 4);
    int* ei      = (int*)alloc(2 * S * 4);
    int* slot_of = (int*)alloc(2 * S * 4);
    int* tlist   = (int*)alloc(NSLOTS * 4);
    int* counts  = (int*)alloc(8 * 4);
    int* offs    = (int*)alloc(8 * 4);
    int* cursor  = (int*)alloc(8 * 4);

    // ---- MoE weight prep: cast + transpose to bf16 [N][K] ----
    castT_kernel<<<dim3(F / 64, D / 64, E), 256, 0, stream>>>(wg, wgt, D, F);
    castT_kernel<<<dim3(F / 64, D / 64, E), 256, 0, stream>>>(wu, wut, D, F);
    castT_kernel<<<dim3(D / 64, F / 64, E), 256, 0, stream>>>(wd, wdt, F, D);

    // ---- attention sub-block (fp32 — keeps router logits bit-stable) ----
    ln_kernel<<<S, 256, 0, stream>>>(hs, ln1w, ln1b, xbuf, nullptr);
    gemm_qkv<<<dim3(D / 64, S / 64, 3), 256, 0, stream>>>(xbuf, wq, wk, wv, qb, kb, vb);
    rope_kernel<<<S, 512, 0, stream>>>(qb, kb);
    attn_flash<<<dim3(16, H), 256, 0, stream>>>(qb, kb, vb, attnb);
    gemm_wo<<<dim3(D / 64, S / 64), 256, 0, stream>>>(attnb, wo, hs, hs2);

    // ---- MoE sub-block (routing fp32; expert GEMMs bf16 MFMA) ----
    ln_kernel<<<S, 256, 0, stream>>>(hs2, ln2w, ln2b, xf32, xbf);
    zero_kernel<<<1, 64, 0, stream>>>(counts, prob_sums, z_sum);
    router_kernel<<<S, 64, 0, stream>>>(xf32, wr, ei, ewb, counts, prob_sums, z_sum);
    finalize_kernel<<<1, 64, 0, stream>>>(counts, prob_sums, z_sum, offs, cursor, out + TD);
    scatter_kernel<<<S / 256, 256, 0, stream>>>(ei, cursor, tlist, slot_of);
    gather_kernel<<<NPAD, 256, 0, stream>>>(xbf, tlist, xg);
    moe_gateup_mfma<<<dim3(F / 128, NSLOTS / 128, E), 256, 0, stream>>>(xg, wgt, wut, Hb, offs, counts);
    moe_down_mfma<<<dim3(D / 128, NSLOTS / 128, E), 256, 0, stream>>>(Hb, wdt, yb, offs, counts);
    combine_kernel<<<S, 256, 0, stream>>>(hs2, yb, ewb, slot_of, out);
}

// Round 5
// 1075.321 us; speedup vs baseline: 2.7450x; 1.0201x over previous
//
#include <hip/hip_runtime.h>
#include <math.h>

static constexpr int S = 2048;          // tokens (B=1)
static constexpr int D = 1024;          // model dim
static constexpr int H = 16;            // heads
static constexpr int HD = 64;           // head dim
static constexpr int E = 8;             // experts
static constexpr int F = 2048;          // ffn dim
static constexpr int NSLOTS = S * 2;    // 4096
static constexpr int NPAD = NSLOTS + 128;

typedef __attribute__((ext_vector_type(8))) short bf16x8;
typedef __attribute__((ext_vector_type(4))) float f32x4;

__device__ __forceinline__ float bf2f(ushort u) {
    uint32_t x = ((uint32_t)u) << 16; float f; __builtin_memcpy(&f, &x, 4); return f;
}
__device__ __forceinline__ ushort f2bf(float f) {
    uint32_t x; __builtin_memcpy(&x, &f, 4);
    return (ushort)((x + 0x7fffu + ((x >> 16) & 1u)) >> 16);
}
__device__ __forceinline__ void async_copy16(const void* gptr, void* ldsptr) {
    __builtin_amdgcn_global_load_lds(
        (const __attribute__((address_space(1))) void*)gptr,
        (__attribute__((address_space(3))) void*)ldsptr, 16, 0, 0);
}

// ============ cast + transpose fp32 [K][N] -> bf16 [N][K] (single plane, MoE weights) ============
__global__ __launch_bounds__(256) void castT_kernel(const float* __restrict__ src,
    ushort* __restrict__ dst, int K, int N)
{
    __shared__ float T[64][65];
    int z = blockIdx.z;
    src += (size_t)z * K * N; dst += (size_t)z * K * N;
    int k0 = blockIdx.y * 64, n0 = blockIdx.x * 64;
    int t = threadIdx.x;
    int r = t >> 4, c4 = (t & 15) * 4;
#pragma unroll
    for (int it = 0; it < 4; it++) {
        float4 v = *(const float4*)(src + (size_t)(k0 + r + it * 16) * N + n0 + c4);
        T[r + it * 16][c4 + 0] = v.x; T[r + it * 16][c4 + 1] = v.y;
        T[r + it * 16][c4 + 2] = v.z; T[r + it * 16][c4 + 3] = v.w;
    }
    __syncthreads();
#pragma unroll
    for (int it = 0; it < 4; it++) {
        int rr = r + it * 16;
        ushort4 o;
        o.x = f2bf(T[c4 + 0][rr]); o.y = f2bf(T[c4 + 1][rr]);
        o.z = f2bf(T[c4 + 2][rr]); o.w = f2bf(T[c4 + 3][rr]);
        *(ushort4*)(dst + (size_t)(n0 + rr) * K + k0 + c4) = o;
    }
}

// ============ cast + transpose fp32 [K][N] -> bf16x2 hi/lo planes [N][K] ============
__global__ __launch_bounds__(256) void castT2_kernel(const float* __restrict__ src,
    ushort* __restrict__ dh, ushort* __restrict__ dl, int K, int N)
{
    __shared__ float T[64][65];
    src += (size_t)blockIdx.z * K * N;
    dh += (size_t)blockIdx.z * K * N; dl += (size_t)blockIdx.z * K * N;
    int k0 = blockIdx.y * 64, n0 = blockIdx.x * 64;
    int t = threadIdx.x;
    int r = t >> 4, c4 = (t & 15) * 4;
#pragma unroll
    for (int it = 0; it < 4; it++) {
        float4 v = *(const float4*)(src + (size_t)(k0 + r + it * 16) * N + n0 + c4);
        T[r + it * 16][c4 + 0] = v.x; T[r + it * 16][c4 + 1] = v.y;
        T[r + it * 16][c4 + 2] = v.z; T[r + it * 16][c4 + 3] = v.w;
    }
    __syncthreads();
#pragma unroll
    for (int it = 0; it < 4; it++) {
        int rr = r + it * 16;
        ushort4 oh, ol;
        float v0 = T[c4 + 0][rr], v1 = T[c4 + 1][rr], v2 = T[c4 + 2][rr], v3 = T[c4 + 3][rr];
        oh.x = f2bf(v0); ol.x = f2bf(v0 - bf2f(oh.x));
        oh.y = f2bf(v1); ol.y = f2bf(v1 - bf2f(oh.y));
        oh.z = f2bf(v2); ol.z = f2bf(v2 - bf2f(oh.z));
        oh.w = f2bf(v3); ol.w = f2bf(v3 - bf2f(oh.w));
        *(ushort4*)(dh + (size_t)(n0 + rr) * K + k0 + c4) = oh;
        *(ushort4*)(dl + (size_t)(n0 + rr) * K + k0 + c4) = ol;
    }
}

// ============ LayerNorm: optional fp32 / bf16-hi / bf16-lo outputs ============
__global__ __launch_bounds__(256) void ln_kernel(const float* __restrict__ x,
    const float* __restrict__ w, const float* __restrict__ b,
    float* __restrict__ yf, ushort* __restrict__ yh, ushort* __restrict__ yl)
{
    int t = blockIdx.x, tid = threadIdx.x;
    __shared__ float redx[256];
    __shared__ float redy[256];
    const float* xr = x + (size_t)t * D;
    float4 xv = *(const float4*)(xr + tid * 4);
    redx[tid] = xv.x + xv.y + xv.z + xv.w;
    redy[tid] = xv.x * xv.x + xv.y * xv.y + xv.z * xv.z + xv.w * xv.w;
    __syncthreads();
    for (int st = 128; st > 0; st >>= 1) {
        if (tid < st) { redx[tid] += redx[tid + st]; redy[tid] += redy[tid + st]; }
        __syncthreads();
    }
    float mean = redx[0] * (1.0f / D);
    float var  = redy[0] * (1.0f / D) - mean * mean;
    float rstd = rsqrtf(var + 1e-5f);
    float4 wv = *(const float4*)(w + tid * 4);
    float4 bv = *(const float4*)(b + tid * 4);
    float4 o;
    o.x = (xv.x - mean) * rstd * wv.x + bv.x;
    o.y = (xv.y - mean) * rstd * wv.y + bv.y;
    o.z = (xv.z - mean) * rstd * wv.z + bv.z;
    o.w = (xv.w - mean) * rstd * wv.w + bv.w;
    if (yf) *(float4*)(yf + (size_t)t * D + tid * 4) = o;
    ushort4 oh;
    oh.x = f2bf(o.x); oh.y = f2bf(o.y); oh.z = f2bf(o.z); oh.w = f2bf(o.w);
    if (yh) *(ushort4*)(yh + (size_t)t * D + tid * 4) = oh;
    if (yl) {
        ushort4 ol;
        ol.x = f2bf(o.x - bf2f(oh.x)); ol.y = f2bf(o.y - bf2f(oh.y));
        ol.z = f2bf(o.z - bf2f(oh.z)); ol.w = f2bf(o.w - bf2f(oh.w));
        *(ushort4*)(yl + (size_t)t * D + tid * 4) = ol;
    }
}

// ============ RoPE (in-place on fp32 q,k) ============
__global__ __launch_bounds__(512) void rope_kernel(float* __restrict__ q, float* __restrict__ k)
{
    int t = blockIdx.x;
    int idx = threadIdx.x;
    int h = idx >> 5, i = idx & 31;
    float invf = powf(10000.0f, -(float)i / 32.0f);
    float ang = (float)t * invf;
    float c = cosf(ang), s = sinf(ang);
    size_t base = (size_t)t * D + h * HD + i;
    float q1 = q[base], q2 = q[base + 32];
    q[base]      = q1 * c - q2 * s;
    q[base + 32] = q2 * c + q1 * s;
    float k1 = k[base], k2 = k[base + 32];
    k[base]      = k1 * c - k2 * s;
    k[base + 32] = k2 * c + k1 * s;
}

// ============ bf16x2 (fp32-emulated) MFMA k-loop: 128x128 tile, BK=32 ============
// acc += (Ah+Al) * (Bh+Bl)^T dropping Al*Bl (error ~2^-18 rel)
__device__ __forceinline__ void mfma2_kloop(const ushort* __restrict__ Ah_g,
    const ushort* __restrict__ Al_g, const ushort* __restrict__ Bh_g,
    const ushort* __restrict__ Bl_g, int lda, int ldb, int K,
    ushort* sAh, ushort* sAl, ushort* sBh, ushort* sBl, f32x4 (&acc)[4][4])
{
    const int tid = threadIdx.x;
    const int w = tid >> 6, l = tid & 63;
    const int wm = (w >> 1) * 64, wn = (w & 1) * 64;
    const int kc = l >> 4, lr = l & 15;
    for (int k0 = 0; k0 < K; k0 += 32) {
#pragma unroll
        for (int it = 0; it < 2; it++) {
            int c = it * 256 + tid;
            int ckc = c >> 7, r = c & 127;
            int loff = (it * 256 + w * 64) * 8;
            size_t ga = (size_t)r * lda + k0 + ckc * 8;
            size_t gb = (size_t)r * ldb + k0 + ckc * 8;
            async_copy16(Ah_g + ga, sAh + loff);
            async_copy16(Al_g + ga, sAl + loff);
            async_copy16(Bh_g + gb, sBh + loff);
            async_copy16(Bl_g + gb, sBl + loff);
        }
        __syncthreads();
        bf16x8 ah[4], al[4], bh[4], bl[4];
#pragma unroll
        for (int f = 0; f < 4; f++) {
            int ao = (kc * 128 + wm + f * 16 + lr) * 8;
            int bo = (kc * 128 + wn + f * 16 + lr) * 8;
            ah[f] = *(const bf16x8*)(sAh + ao);
            al[f] = *(const bf16x8*)(sAl + ao);
            bh[f] = *(const bf16x8*)(sBh + bo);
            bl[f] = *(const bf16x8*)(sBl + bo);
        }
#pragma unroll
        for (int fm = 0; fm < 4; fm++)
#pragma unroll
            for (int fn = 0; fn < 4; fn++) {
                acc[fm][fn] = __builtin_amdgcn_mfma_f32_16x16x32_bf16(ah[fm], bh[fn], acc[fm][fn], 0, 0, 0);
                acc[fm][fn] = __builtin_amdgcn_mfma_f32_16x16x32_bf16(ah[fm], bl[fn], acc[fm][fn], 0, 0, 0);
                acc[fm][fn] = __builtin_amdgcn_mfma_f32_16x16x32_bf16(al[fm], bh[fn], acc[fm][fn], 0, 0, 0);
            }
        __syncthreads();
    }
}

// ============ QKV GEMM bf16x2 -> fp32 out (z selects q/k/v) ============
__global__ __launch_bounds__(256) void qkv_mfma2(const ushort* __restrict__ xh,
    const ushort* __restrict__ xl,
    const ushort* __restrict__ wqh, const ushort* __restrict__ wql,
    const ushort* __restrict__ wkh, const ushort* __restrict__ wkl,
    const ushort* __restrict__ wvh, const ushort* __restrict__ wvl,
    float* __restrict__ qo, float* __restrict__ ko, float* __restrict__ vo)
{
    __shared__ ushort sAh[4096], sAl[4096], sBh[4096], sBl[4096];
    const ushort* Bh = blockIdx.z == 0 ? wqh : (blockIdx.z == 1 ? wkh : wvh);
    const ushort* Bl = blockIdx.z == 0 ? wql : (blockIdx.z == 1 ? wkl : wvl);
    float* C = blockIdx.z == 0 ? qo : (blockIdx.z == 1 ? ko : vo);
    int m0 = blockIdx.y * 128, n0 = blockIdx.x * 128;
    f32x4 acc[4][4];
#pragma unroll
    for (int i = 0; i < 4; i++)
#pragma unroll
        for (int j = 0; j < 4; j++) acc[i][j] = (f32x4){0.f, 0.f, 0.f, 0.f};
    mfma2_kloop(xh + (size_t)m0 * D, xl + (size_t)m0 * D,
                Bh + (size_t)n0 * D, Bl + (size_t)n0 * D, D, D, D,
                sAh, sAl, sBh, sBl, acc);
    const int l = threadIdx.x & 63, w = threadIdx.x >> 6;
    const int wm = (w >> 1) * 64, wn = (w & 1) * 64;
#pragma unroll
    for (int fm = 0; fm < 4; fm++)
#pragma unroll
        for (int fn = 0; fn < 4; fn++)
#pragma unroll
            for (int r = 0; r < 4; r++) {
                int row = m0 + wm + fm * 16 + (l >> 4) * 4 + r;
                int col = n0 + wn + fn * 16 + (l & 15);
                C[(size_t)row * D + col] = acc[fm][fn][r];
            }
}

// ============ WO GEMM bf16x2 + residual -> fp32 ============
__global__ __launch_bounds__(256) void wo_mfma2(const ushort* __restrict__ ah,
    const ushort* __restrict__ al, const ushort* __restrict__ wh, const ushort* __restrict__ wl,
    const float* __restrict__ resid, float* __restrict__ Cout)
{
    __shared__ ushort sAh[4096], sAl[4096], sBh[4096], sBl[4096];
    int m0 = blockIdx.y * 128, n0 = blockIdx.x * 128;
    f32x4 acc[4][4];
#pragma unroll
    for (int i = 0; i < 4; i++)
#pragma unroll
        for (int j = 0; j < 4; j++) acc[i][j] = (f32x4){0.f, 0.f, 0.f, 0.f};
    mfma2_kloop(ah + (size_t)m0 * D, al + (size_t)m0 * D,
                wh + (size_t)n0 * D, wl + (size_t)n0 * D, D, D, D,
                sAh, sAl, sBh, sBl, acc);
    const int l = threadIdx.x & 63, w = threadIdx.x >> 6;
    const int wm = (w >> 1) * 64, wn = (w & 1) * 64;
#pragma unroll
    for (int fm = 0; fm < 4; fm++)
#pragma unroll
        for (int fn = 0; fn < 4; fn++)
#pragma unroll
            for (int r = 0; r < 4; r++) {
                int row = m0 + wm + fm * 16 + (l >> 4) * 4 + r;
                int col = n0 + wn + fn * 16 + (l & 15);
                Cout[(size_t)row * D + col] = acc[fm][fn][r] + resid[(size_t)row * D + col];
            }
}

// ============ Flash attention v2: fp32, paired q-tiles, K dbuf + reg prefetch ============
// Outputs attention result as bf16x2 (hi/lo) planes for the WO bf16x2 GEMM.
__global__ __launch_bounds__(256) void attn_flash(const float* __restrict__ q,
    const float* __restrict__ k, const float* __restrict__ v,
    ushort* __restrict__ oh_out, ushort* __restrict__ ol_out)
{
    __shared__ float QsT[64][64];        // [d][row], pre-scaled
    __shared__ float Ks[2][64][64];      // K^T then P^T (per buffer)
    __shared__ float Vs[64][64];         // [row][d]
    const int h = blockIdx.y;
    const int tid = threadIdx.x;
    const int tx = tid & 15, ty = tid >> 4;
    const size_t hoff = (size_t)h * HD;
    const int lrow = tid >> 2;           // 0..63
    const int lc   = tid & 3;

    for (int half = 0; half < 2; half++) {
        const int qt = (half == 0) ? (int)blockIdx.x : 31 - (int)blockIdx.x;
        const int r0 = qt * 64;
        // ---- stage Q^T (pre-scaled) ----
#pragma unroll
        for (int l = 0; l < 4; l++) {
            int d0 = lc * 4 + l * 16;
            float4 qv = *(const float4*)(q + (size_t)(r0 + lrow) * D + hoff + d0);
            QsT[d0 + 0][lrow] = qv.x * 0.125f;
            QsT[d0 + 1][lrow] = qv.y * 0.125f;
            QsT[d0 + 2][lrow] = qv.z * 0.125f;
            QsT[d0 + 3][lrow] = qv.w * 0.125f;
        }
        // ---- prefetch tile 0 into regs, store to buf 0 ----
        float4 kreg[4], vreg[4];
#pragma unroll
        for (int l = 0; l < 4; l++) {
            int d0 = lc * 4 + l * 16;
            kreg[l] = *(const float4*)(k + (size_t)(0 + lrow) * D + hoff + d0);
            vreg[l] = *(const float4*)(v + (size_t)(0 + lrow) * D + hoff + d0);
        }
#pragma unroll
        for (int l = 0; l < 4; l++) {
            int d0 = lc * 4 + l * 16;
            Ks[0][d0 + 0][lrow] = kreg[l].x; Ks[0][d0 + 1][lrow] = kreg[l].y;
            Ks[0][d0 + 2][lrow] = kreg[l].z; Ks[0][d0 + 3][lrow] = kreg[l].w;
            *(float4*)&Vs[lrow][d0] = vreg[l];
        }
        float m_[4], l_[4], o_[4][4];
#pragma unroll
        for (int i = 0; i < 4; i++) {
            m_[i] = -3e38f; l_[i] = 0.0f;
#pragma unroll
            for (int j = 0; j < 4; j++) o_[i][j] = 0.0f;
        }
        __syncthreads();   // B1: Q + tile0 staged
        for (int kt = 0; kt <= qt; kt++) {
            const int cur = kt & 1;
            // ---- issue next tile's global loads early (latency hidden by compute) ----
            if (kt < qt) {
#pragma unroll
                for (int l = 0; l < 4; l++) {
                    int d0 = lc * 4 + l * 16;
                    kreg[l] = *(const float4*)(k + (size_t)((kt + 1) * 64 + lrow) * D + hoff + d0);
                    vreg[l] = *(const float4*)(v + (size_t)((kt + 1) * 64 + lrow) * D + hoff + d0);
                }
            }
            // ---- S = Q K^T ----
            float s_[4][4] = {};
#pragma unroll 4
            for (int d = 0; d < 64; d++) {
                float4 qv = *(const float4*)&QsT[d][ty * 4];
                float4 kv = *(const float4*)&Ks[cur][d][tx * 4];
                float a_[4] = {qv.x, qv.y, qv.z, qv.w};
                float b_[4] = {kv.x, kv.y, kv.z, kv.w};
#pragma unroll
                for (int i = 0; i < 4; i++)
#pragma unroll
                    for (int j = 0; j < 4; j++) s_[i][j] = fmaf(a_[i], b_[j], s_[i][j]);
            }
            if (kt == qt) {
#pragma unroll
                for (int i = 0; i < 4; i++)
#pragma unroll
                    for (int j = 0; j < 4; j++)
                        if (tx * 4 + j > ty * 4 + i) s_[i][j] = -1e30f;
            }
            // ---- online softmax (16-lane shuffle) ----
            float p_[4][4], alpha[4];
#pragma unroll
            for (int i = 0; i < 4; i++) {
                float r = fmaxf(fmaxf(s_[i][0], s_[i][1]), fmaxf(s_[i][2], s_[i][3]));
#pragma unroll
                for (int off = 1; off < 16; off <<= 1) r = fmaxf(r, __shfl_xor(r, off));
                float mn = fmaxf(m_[i], r);
                alpha[i] = expf(m_[i] - mn);
                float rs = 0.0f;
#pragma unroll
                for (int j = 0; j < 4; j++) { p_[i][j] = expf(s_[i][j] - mn); rs += p_[i][j]; }
#pragma unroll
                for (int off = 1; off < 16; off <<= 1) rs += __shfl_xor(rs, off);
                l_[i] = l_[i] * alpha[i] + rs;
                m_[i] = mn;
#pragma unroll
                for (int j = 0; j < 4; j++) o_[i][j] *= alpha[i];
            }
            __syncthreads();   // B2: all done reading Ks[cur] as K
            // ---- store P^T as float4 (conflict-light) ----
#pragma unroll
            for (int j = 0; j < 4; j++) {
                float4 pv = make_float4(p_[0][j], p_[1][j], p_[2][j], p_[3][j]);
                *(float4*)&Ks[cur][tx * 4 + j][ty * 4] = pv;
            }
            __syncthreads();   // B3: P ready
            // ---- O += P V ----
#pragma unroll 4
            for (int j = 0; j < 64; j++) {
                float4 pv = *(const float4*)&Ks[cur][j][ty * 4];
                float4 vv = *(const float4*)&Vs[j][tx * 4];
                float a_[4] = {pv.x, pv.y, pv.z, pv.w};
                float b_[4] = {vv.x, vv.y, vv.z, vv.w};
#pragma unroll
                for (int i = 0; i < 4; i++)
#pragma unroll
                    for (int jj = 0; jj < 4; jj++) o_[i][jj] = fmaf(a_[i], b_[jj], o_[i][jj]);
            }
            if (kt < qt) {
                __syncthreads();   // B4: PV reads of Vs done
#pragma unroll
                for (int l = 0; l < 4; l++) {
                    int d0 = lc * 4 + l * 16;
                    Ks[1 - cur][d0 + 0][lrow] = kreg[l].x; Ks[1 - cur][d0 + 1][lrow] = kreg[l].y;
                    Ks[1 - cur][d0 + 2][lrow] = kreg[l].z; Ks[1 - cur][d0 + 3][lrow] = kreg[l].w;
                    *(float4*)&Vs[lrow][d0] = vreg[l];
                }
                __syncthreads();   // B1': next tile staged
            }
        }
        // ---- epilogue: normalize + store bf16x2 ----
#pragma unroll
        for (int i = 0; i < 4; i++) {
            float inv = 1.0f / l_[i];
            ushort4 oh, ol;
            float v0 = o_[i][0] * inv, v1 = o_[i][1] * inv, v2 = o_[i][2] * inv, v3 = o_[i][3] * inv;
            oh.x = f2bf(v0); ol.x = f2bf(v0 - bf2f(oh.x));
            oh.y = f2bf(v1); ol.y = f2bf(v1 - bf2f(oh.y));
            oh.z = f2bf(v2); ol.z = f2bf(v2 - bf2f(oh.z));
            oh.w = f2bf(v3); ol.w = f2bf(v3 - bf2f(oh.w));
            size_t oo = (size_t)(r0 + ty * 4 + i) * D + hoff + tx * 4;
            *(ushort4*)(oh_out + oo) = oh;
            *(ushort4*)(ol_out + oo) = ol;
        }
        __syncthreads();   // before next half re-stages QsT/Ks/Vs
    }
}

// ============ Router (fp32 — routing must match reference exactly) ============
__global__ __launch_bounds__(64) void router_kernel(const float* __restrict__ x,
    const float* __restrict__ wr, int* __restrict__ ei, float* __restrict__ ew,
    int* __restrict__ counts, float* __restrict__ prob_sums, float* __restrict__ z_sum)
{
    int t = blockIdx.x, lane = threadIdx.x;
    const float* xr = x + (size_t)t * D;
    float p[E] = {};
    for (int d = lane; d < D; d += 64) {
        float xd = xr[d];
        const float* wrow = wr + d * E;
#pragma unroll
        for (int e = 0; e < E; e++) p[e] = fmaf(xd, wrow[e], p[e]);
    }
#pragma unroll
    for (int off = 32; off > 0; off >>= 1) {
#pragma unroll
        for (int e = 0; e < E; e++) p[e] += __shfl_xor(p[e], off);
    }
    float m = p[0];
#pragma unroll
    for (int e = 1; e < E; e++) m = fmaxf(m, p[e]);
    float sum = 0.0f, pr[E];
#pragma unroll
    for (int e = 0; e < E; e++) { pr[e] = expf(p[e] - m); sum += pr[e]; }
    float invs = 1.0f / sum;
#pragma unroll
    for (int e = 0; e < E; e++) pr[e] *= invs;
    float lse = m + logf(sum);
    int e1 = 0; float b1 = pr[0];
#pragma unroll
    for (int e = 1; e < E; e++) if (pr[e] > b1) { b1 = pr[e]; e1 = e; }
    int e2 = -1; float b2 = -1.0f;
#pragma unroll
    for (int e = 0; e < E; e++) if (e != e1 && pr[e] > b2) { b2 = pr[e]; e2 = e; }
    float wsum = b1 + b2;
    if (lane == 0) {
        ei[2 * t] = e1; ei[2 * t + 1] = e2;
        ew[2 * t] = b1 / wsum; ew[2 * t + 1] = b2 / wsum;
        atomicAdd(&counts[e1], 1);
        atomicAdd(&counts[e2], 1);
        atomicAdd(z_sum, lse * lse);
    }
    if (lane < E) atomicAdd(&prob_sums[lane], pr[lane]);
}

__global__ void zero_kernel(int* counts, float* prob_sums, float* z_sum)
{
    int tid = threadIdx.x;
    if (tid < E) { counts[tid] = 0; prob_sums[tid] = 0.0f; }
    if (tid == 0) *z_sum = 0.0f;
}

__global__ void finalize_kernel(const int* __restrict__ counts, const float* __restrict__ prob_sums,
    const float* __restrict__ z_sum, int* __restrict__ offs, int* __restrict__ cursor,
    float* __restrict__ aux_out)
{
    if (threadIdx.x == 0) {
        int off = 0;
        for (int e = 0; e < E; e++) { offs[e] = off; cursor[e] = off; off += counts[e]; }
        float z = 1e-3f * (*z_sum) * (1.0f / S);
        float lb = 0.0f;
        for (int e = 0; e < E; e++) lb += ((float)counts[e] / (float)S) * (prob_sums[e] / (float)S);
        lb *= 1e-2f;
        *aux_out = z + lb;
    }
}

__global__ __launch_bounds__(256) void scatter_kernel(const int* __restrict__ ei,
    int* __restrict__ cursor, int* __restrict__ tlist, int* __restrict__ slot_of)
{
    int t = blockIdx.x * 256 + threadIdx.x;
    if (t >= S) return;
#pragma unroll
    for (int kk = 0; kk < 2; kk++) {
        int e = ei[2 * t + kk];
        int slot = atomicAdd(&cursor[e], 1);
        tlist[slot] = t;
        slot_of[2 * t + kk] = slot;
    }
}

__global__ __launch_bounds__(256) void gather_kernel(const ushort* __restrict__ xbf,
    const int* __restrict__ tlist, ushort* __restrict__ xg)
{
    int slot = blockIdx.x;
    int t4 = threadIdx.x * 4;
    ushort4 vv;
    if (slot < NSLOTS) {
        int tok = tlist[slot];
        vv = *(const ushort4*)(xbf + (size_t)tok * D + t4);
    } else {
        vv = make_ushort4(0, 0, 0, 0);
    }
    *(ushort4*)(xg + (size_t)slot * D + t4) = vv;
}

// ============ MoE fused gate+up MFMA GEMM + SiLU epilogue (BK=64) ============
__global__ __launch_bounds__(256) void moe_gateup_mfma(const ushort* __restrict__ xg,
    const ushort* __restrict__ wgt, const ushort* __restrict__ wut,
    ushort* __restrict__ Hb, const int* __restrict__ offs, const int* __restrict__ cnts)
{
    int e = blockIdx.z;
    int cnt = cnts[e];
    int m0 = blockIdx.y * 128;
    if (m0 >= cnt) return;
    int off = offs[e];
    const ushort* Gt = wgt + (size_t)e * F * D;
    const ushort* Ut = wut + (size_t)e * F * D;
    int n0 = blockIdx.x * 128;
    __shared__ ushort As[8192], Gs[8192], Us[8192];
    const int tid = threadIdx.x;
    const int w = tid >> 6, l = tid & 63;
    const int wm = (w >> 1) * 64, wn = (w & 1) * 64;
    const ushort* Arow = xg + (size_t)(off + m0) * D;
    const ushort* Grow = Gt + (size_t)n0 * D;
    const ushort* Urow = Ut + (size_t)n0 * D;
    f32x4 accg[4][4], accu[4][4];
#pragma unroll
    for (int i = 0; i < 4; i++)
#pragma unroll
        for (int j = 0; j < 4; j++) { accg[i][j] = (f32x4){0.f,0.f,0.f,0.f}; accu[i][j] = (f32x4){0.f,0.f,0.f,0.f}; }
    for (int k0 = 0; k0 < D; k0 += 64) {
#pragma unroll
        for (int it = 0; it < 4; it++) {
            int c = it * 256 + tid;
            int kc = c >> 7, r = c & 127;
            async_copy16(Arow + (size_t)r * D + k0 + kc * 8, As + (size_t)(it * 256 + w * 64) * 8);
            async_copy16(Grow + (size_t)r * D + k0 + kc * 8, Gs + (size_t)(it * 256 + w * 64) * 8);
            async_copy16(Urow + (size_t)r * D + k0 + kc * 8, Us + (size_t)(it * 256 + w * 64) * 8);
        }
        __syncthreads();
#pragma unroll
        for (int hh = 0; hh < 2; hh++) {
            bf16x8 af[4], gf[4], uf[4];
            int kc = hh * 4 + (l >> 4);
#pragma unroll
            for (int f = 0; f < 4; f++) {
                af[f] = *(const bf16x8*)(As + (size_t)(kc * 128 + wm + f * 16 + (l & 15)) * 8);
                gf[f] = *(const bf16x8*)(Gs + (size_t)(kc * 128 + wn + f * 16 + (l & 15)) * 8);
                uf[f] = *(const bf16x8*)(Us + (size_t)(kc * 128 + wn + f * 16 + (l & 15)) * 8);
            }
#pragma unroll
            for (int fm = 0; fm < 4; fm++)
#pragma unroll
                for (int fn = 0; fn < 4; fn++) {
                    accg[fm][fn] = __builtin_amdgcn_mfma_f32_16x16x32_bf16(af[fm], gf[fn], accg[fm][fn], 0, 0, 0);
                    accu[fm][fn] = __builtin_amdgcn_mfma_f32_16x16x32_bf16(af[fm], uf[fn], accu[fm][fn], 0, 0, 0);
                }
        }
        __syncthreads();
    }
#pragma unroll
    for (int fm = 0; fm < 4; fm++)
#pragma unroll
        for (int fn = 0; fn < 4; fn++)
#pragma unroll
            for (int r = 0; r < 4; r++) {
                int rloc = m0 + wm + fm * 16 + (l >> 4) * 4 + r;
                if (rloc < cnt) {
                    int col = n0 + wn + fn * 16 + (l & 15);
                    float g = accg[fm][fn][r], u = accu[fm][fn][r];
                    Hb[(size_t)(off + rloc) * F + col] = f2bf(g / (1.0f + expf(-g)) * u);
                }
            }
}

// ============ MoE down MFMA GEMM (BK=64) ============
__global__ __launch_bounds__(256) void moe_down_mfma(const ushort* __restrict__ Hb,
    const ushort* __restrict__ wdt, ushort* __restrict__ yb,
    const int* __restrict__ offs, const int* __restrict__ cnts)
{
    int e = blockIdx.z;
    int cnt = cnts[e];
    int m0 = blockIdx.y * 128;
    if (m0 >= cnt) return;
    int off = offs[e];
    const ushort* Bt = wdt + (size_t)e * D * F;
    int n0 = blockIdx.x * 128;
    __shared__ ushort As[8192], Bs[8192];
    const int tid = threadIdx.x;
    const int w = tid >> 6, l = tid & 63;
    const int wm = (w >> 1) * 64, wn = (w & 1) * 64;
    const ushort* Arow = Hb + (size_t)(off + m0) * F;
    const ushort* Brow = Bt + (size_t)n0 * F;
    f32x4 acc[4][4];
#pragma unroll
    for (int i = 0; i < 4; i++)
#pragma unroll
        for (int j = 0; j < 4; j++) acc[i][j] = (f32x4){0.f,0.f,0.f,0.f};
    for (int k0 = 0; k0 < F; k0 += 64) {
#pragma unroll
        for (int it = 0; it < 4; it++) {
            int c = it * 256 + tid;
            int kc = c >> 7, r = c & 127;
            async_copy16(Arow + (size_t)r * F + k0 + kc * 8, As + (size_t)(it * 256 + w * 64) * 8);
            async_copy16(Brow + (size_t)r * F + k0 + kc * 8, Bs + (size_t)(it * 256 + w * 64) * 8);
        }
        __syncthreads();
#pragma unroll
        for (int hh = 0; hh < 2; hh++) {
            bf16x8 af[4], bfr[4];
            int kc = hh * 4 + (l >> 4);
#pragma unroll
            for (int f = 0; f < 4; f++) {
                af[f]  = *(const bf16x8*)(As + (size_t)(kc * 128 + wm + f * 16 + (l & 15)) * 8);
                bfr[f] = *(const bf16x8*)(Bs + (size_t)(kc * 128 + wn + f * 16 + (l & 15)) * 8);
            }
#pragma unroll
            for (int fm = 0; fm < 4; fm++)
#pragma unroll
                for (int fn = 0; fn < 4; fn++)
                    acc[fm][fn] = __builtin_amdgcn_mfma_f32_16x16x32_bf16(af[fm], bfr[fn], acc[fm][fn], 0, 0, 0);
        }
        __syncthreads();
    }
#pragma unroll
    for (int fm = 0; fm < 4; fm++)
#pragma unroll
        for (int fn = 0; fn < 4; fn++)
#pragma unroll
            for (int r = 0; r < 4; r++) {
                int rloc = m0 + wm + fm * 16 + (l >> 4) * 4 + r;
                if (rloc < cnt) {
                    int col = n0 + wn + fn * 16 + (l & 15);
                    yb[(size_t)(off + rloc) * D + col] = f2bf(acc[fm][fn][r]);
                }
            }
}

// ============ Combine ============
__global__ __launch_bounds__(256) void combine_kernel(const float* __restrict__ hs2,
    const ushort* __restrict__ yb, const float* __restrict__ ew,
    const int* __restrict__ slot_of, float* __restrict__ out)
{
    int t = blockIdx.x, tid = threadIdx.x;
    int s0 = slot_of[2 * t], s1 = slot_of[2 * t + 1];
    float w0 = ew[2 * t], w1 = ew[2 * t + 1];
    float4 a = *(const float4*)(hs2 + (size_t)t * D + tid * 4);
    ushort4 y0 = *(const ushort4*)(yb + (size_t)s0 * D + tid * 4);
    ushort4 y1 = *(const ushort4*)(yb + (size_t)s1 * D + tid * 4);
    float4 o;
    o.x = a.x + w0 * bf2f(y0.x) + w1 * bf2f(y1.x);
    o.y = a.y + w0 * bf2f(y0.y) + w1 * bf2f(y1.y);
    o.z = a.z + w0 * bf2f(y0.z) + w1 * bf2f(y1.z);
    o.w = a.w + w0 * bf2f(y0.w) + w1 * bf2f(y1.w);
    *(float4*)(out + (size_t)t * D + tid * 4) = o;
}

// ============ launch ============
extern "C" void kernel_launch(void* const* d_in, const int* in_sizes, int n_in,
                              void* d_out, int out_size, void* d_ws, size_t ws_size,
                              hipStream_t stream)
{
    (void)in_sizes; (void)n_in; (void)out_size; (void)ws_size;
    const float* hs   = (const float*)d_in[0];
    const float* ln1w = (const float*)d_in[3];
    const float* ln1b = (const float*)d_in[4];
    const float* ln2w = (const float*)d_in[5];
    const float* ln2b = (const float*)d_in[6];
    const float* wq   = (const float*)d_in[7];
    const float* wk   = (const float*)d_in[8];
    const float* wv   = (const float*)d_in[9];
    const float* wo   = (const float*)d_in[10];
    const float* wr   = (const float*)d_in[11];
    const float* wg   = (const float*)d_in[12];
    const float* wu   = (const float*)d_in[13];
    const float* wd   = (const float*)d_in[14];
    float* out = (float*)d_out;

    const size_t TD = (size_t)S * D;
    char* p = (char*)d_ws;
    auto alloc = [&](size_t bytes) { char* r = p; p += (bytes + 255) & ~(size_t)255; return r; };

    ushort* wgt  = (ushort*)alloc((size_t)E * D * F * 2);
    ushort* wut  = (ushort*)alloc((size_t)E * D * F * 2);
    ushort* wdt  = (ushort*)alloc((size_t)E * D * F * 2);
    ushort* wqh  = (ushort*)alloc((size_t)D * D * 2);
    ushort* wqlo = (ushort*)alloc((size_t)D * D * 2);
    ushort* wkh  = (ushort*)alloc((size_t)D * D * 2);
    ushort* wklo = (ushort*)alloc((size_t)D * D * 2);
    ushort* wvh  = (ushort*)alloc((size_t)D * D * 2);
    ushort* wvlo = (ushort*)alloc((size_t)D * D * 2);
    ushort* woh  = (ushort*)alloc((size_t)D * D * 2);
    ushort* wolo = (ushort*)alloc((size_t)D * D * 2);
    ushort* xh   = (ushort*)alloc(TD * 2);
    ushort* xl   = (ushort*)alloc(TD * 2);
    float*  qb   = (float*)alloc(TD * 4);
    float*  kb   = (float*)alloc(TD * 4);
    float*  vb   = (float*)alloc(TD * 4);
    ushort* ath  = (ushort*)alloc(TD * 2);
    ushort* atl  = (ushort*)alloc(TD * 2);
    float*  hs2  = (float*)alloc(TD * 4);
    float*  xf32 = (float*)alloc(TD * 4);
    ushort* xbf  = (ushort*)alloc(TD * 2);
    ushort* xg   = (ushort*)alloc((size_t)NPAD * D * 2);
    ushort* Hb   = (ushort*)alloc((size_t)NPAD * F * 2);
    ushort* yb   = (ushort*)alloc((size_t)NPAD * D * 2);
    float*  ewb       = (float*)alloc(2 * S * 4);
    float*  prob_sums = (float*)alloc(8 * 4);
    float*  z_sum     = (float*)alloc(8 * 4);
    int* ei      = (int*)alloc(2 * S * 4);
    int* slot_of = (int*)alloc(2 * S * 4);
    int* tlist   = (int*)alloc(NSLOTS * 4);
    int* counts  = (int*)alloc(8 * 4);
    int* offs    = (int*)alloc(8 * 4);
    int* cursor  = (int*)alloc(8 * 4);

    // ---- weight prep ----
    castT2_kernel<<<dim3(D / 64, D / 64, 1), 256, 0, stream>>>(wq, wqh, wqlo, D, D);
    castT2_kernel<<<dim3(D / 64, D / 64, 1), 256, 0, stream>>>(wk, wkh, wklo, D, D);
    castT2_kernel<<<dim3(D / 64, D / 64, 1), 256, 0, stream>>>(wv, wvh, wvlo, D, D);
    castT2_kernel<<<dim3(D / 64, D / 64, 1), 256, 0, stream>>>(wo, woh, wolo, D, D);
    castT_kernel<<<dim3(F / 64, D / 64, E), 256, 0, stream>>>(wg, wgt, D, F);
    castT_kernel<<<dim3(F / 64, D / 64, E), 256, 0, stream>>>(wu, wut, D, F);
    castT_kernel<<<dim3(D / 64, F / 64, E), 256, 0, stream>>>(wd, wdt, F, D);

    // ---- attention sub-block (bf16x2 GEMMs ~ fp32 accuracy; routing stays stable) ----
    ln_kernel<<<S, 256, 0, stream>>>(hs, ln1w, ln1b, nullptr, xh, xl);
    qkv_mfma2<<<dim3(D / 128, S / 128, 3), 256, 0, stream>>>(xh, xl, wqh, wqlo, wkh, wklo, wvh, wvlo, qb, kb, vb);
    rope_kernel<<<S, 512, 0, stream>>>(qb, kb);
    attn_flash<<<dim3(16, H), 256, 0, stream>>>(qb, kb, vb, ath, atl);
    wo_mfma2<<<dim3(D / 128, S / 128), 256, 0, stream>>>(ath, atl, woh, wolo, hs, hs2);

    // ---- MoE sub-block ----
    ln_kernel<<<S, 256, 0, stream>>>(hs2, ln2w, ln2b, xf32, xbf, nullptr);
    zero_kernel<<<1, 64, 0, stream>>>(counts, prob_sums, z_sum);
    router_kernel<<<S, 64, 0, stream>>>(xf32, wr, ei, ewb, counts, prob_sums, z_sum);
    finalize_kernel<<<1, 64, 0, stream>>>(counts, prob_sums, z_sum, offs, cursor, out + TD);
    scatter_kernel<<<S / 256, 256, 0, stream>>>(ei, cursor, tlist, slot_of);
    gather_kernel<<<NPAD, 256, 0, stream>>>(xbf, tlist, xg);
    moe_gateup_mfma<<<dim3(F / 128, NSLOTS / 128, E), 256, 0, stream>>>(xg, wgt, wut, Hb, offs, counts);
    moe_down_mfma<<<dim3(D / 128, NSLOTS / 128, E), 256, 0, stream>>>(Hb, wdt, yb, offs, counts);
    combine_kernel<<<S, 256, 0, stream>>>(hs2, yb, ewb, slot_of, out);
}